// Round 7
// baseline (550.071 us; speedup 1.0000x reference)
//
#include <hip/hip_runtime.h>
#include <hip/hip_bf16.h>
#include <hip/amd_detail/amd_hip_vector_types.h>

#define NPTS 8192
#define PP 2048
#define KNN 30
#define KTOT 31
#define HEADS 3
#define LDH 352   // padded ld for link4 hi/lo (bf16): >= Kpad32(326), mult of 8
#define NSEG 9
#define LDZ 200   // z ld stages 1-2 (fp32): 198 cols = 192 proj + 3 s + 3 t
#define LDZB3 200 // z ld stage 3 (bf16 ushorts)
#define LDZB4 392 // z ld stage 4 (bf16 ushorts): 390 cols = 384 proj + 3 s + 3 t

typedef __attribute__((ext_vector_type(8))) short short8;
typedef __attribute__((ext_vector_type(4))) float floatx4;
typedef __attribute__((ext_vector_type(4))) unsigned int uint4_t;
typedef unsigned short ushort_t;
typedef unsigned int uint_t;

__device__ inline ushort_t f2bs(float v) {
    __hip_bfloat16 b = __float2bfloat16(v);
    return *reinterpret_cast<ushort_t*>(&b);
}
__device__ inline float bs2f(ushort_t u) {
    __hip_bfloat16 b = *reinterpret_cast<__hip_bfloat16*>(&u);
    return __bfloat162float(b);
}
__device__ inline void split2(float v, ushort_t& h, ushort_t& l) {
    h = f2bs(v);
    l = f2bs(v - bs2f(h));
}
// order-preserving fp32 <-> uint mapping for atomic max
__device__ inline uint_t fenc(float f) {
    uint_t b = __float_as_uint(f);
    return (b & 0x80000000u) ? ~b : (b | 0x80000000u);
}
__device__ inline float fdec(uint_t e) {
    return __uint_as_float((e & 0x80000000u) ? (e & 0x7FFFFFFFu) : ~e);
}

// ---------------- build x0 (hi/lo) into link4 cols 0..5 ----------------
__global__ void k_build_x0(const float* __restrict__ x, const float* __restrict__ pos,
                           ushort_t* __restrict__ lh, ushort_t* __restrict__ ll) {
    int i = blockIdx.x * blockDim.x + threadIdx.x;
    if (i >= NPTS * 6) return;
    int n = i / 6, c = i % 6;
    float v = (c < 3) ? x[n * 3 + c] : pos[n * 3 + (c - 3)];
    ushort_t h, l; split2(v, h, l);
    lh[(size_t)n * LDH + c] = h;
    ll[(size_t)n * LDH + c] = l;
}

// ---------------- fused stage-1 KNN: C=6 coords fit LDS -> no key round-trip --------
// block = 4 rows of one cloud; coords staged transposed (lane-consecutive j ->
// conflict-free); exact fp32 distances; register top-30 selection (as k_topk).
__global__ __launch_bounds__(256)
void k_knn6(const float* __restrict__ x, const float* __restrict__ pos,
            int* __restrict__ nbr) {
    __shared__ float cs[6][PP];
    __shared__ float sq[PP];
    int tid = threadIdx.x;
    int r0 = blockIdx.x * 4;
    int cb = (r0 / PP) * PP;
    for (int j = tid; j < PP; j += 256) {
        float a0 = x[(size_t)(cb + j) * 3 + 0];
        float a1 = x[(size_t)(cb + j) * 3 + 1];
        float a2 = x[(size_t)(cb + j) * 3 + 2];
        float p0 = pos[(size_t)(cb + j) * 3 + 0];
        float p1 = pos[(size_t)(cb + j) * 3 + 1];
        float p2 = pos[(size_t)(cb + j) * 3 + 2];
        cs[0][j] = a0; cs[1][j] = a1; cs[2][j] = a2;
        cs[3][j] = p0; cs[4][j] = p1; cs[5][j] = p2;
        sq[j] = a0 * a0 + a1 * a1 + a2 * a2 + p0 * p0 + p1 * p1 + p2 * p2;
    }
    __syncthreads();
    int w = tid >> 6, lane = tid & 63;
    int rl = (r0 - cb) + w;
    float c0 = cs[0][rl], c1 = cs[1][rl], c2 = cs[2][rl],
          c3 = cs[3][rl], c4 = cs[4][rl], c5 = cs[5][rl];
    float sqr = sq[rl];
    uint_t v[32];
#pragma unroll
    for (int j8 = 0; j8 < 8; j8++)
#pragma unroll
        for (int t = 0; t < 4; t++) {
            int jl = j8 * 256 + t * 64 + lane;
            float dot = c0 * cs[0][jl] + c1 * cs[1][jl] + c2 * cs[2][jl]
                      + c3 * cs[3][jl] + c4 * cs[4][jl] + c5 * cs[5][jl];
            float dd = sqr + sq[jl] - 2.f * dot;
            dd = (jl == rl) ? 3e9f : fmaxf(dd, 0.f);
            v[j8 * 4 + t] = (__float_as_uint(dd) & 0xFFFFF800u) | (uint_t)jl;
        }
    uint_t g[8];
#pragma unroll
    for (int j = 0; j < 8; j++)
        g[j] = min(min(v[j * 4], v[j * 4 + 1]), min(v[j * 4 + 2], v[j * 4 + 3]));
    uint_t lv = g[0];
#pragma unroll
    for (int j = 1; j < 8; j++) lv = min(lv, g[j]);
    int r = cb + rl;
    for (int sel = 0; sel < KNN; sel++) {
        uint_t bk = lv;
#pragma unroll
        for (int off = 32; off > 0; off >>= 1)
            bk = min(bk, (uint_t)__shfl_xor((int)bk, off, 64));
        uint_t bks = __builtin_amdgcn_readfirstlane(bk);
        if (lane == 0) nbr[r * KTOT + sel] = cb + (int)(bks & 0x7FFu);
        int grp = (int)((bks & 0x7FFu) >> 8);
#pragma unroll
        for (int jj = 0; jj < 8; jj++)
            if (grp == jj) {
#pragma unroll
                for (int t = 0; t < 4; t++)
                    v[jj * 4 + t] = (v[jj * 4 + t] == bks) ? 0xFFFFFFFFu : v[jj * 4 + t];
                g[jj] = min(min(v[jj * 4], v[jj * 4 + 1]), min(v[jj * 4 + 2], v[jj * 4 + 3]));
            }
        lv = g[0];
#pragma unroll
        for (int j = 1; j < 8; j++) lv = min(lv, g[j]);
    }
    if (lane == 0) nbr[r * KTOT + KNN] = r;
}

// ---------------- combined GAT weights: Wc = [W*blkdiag(mlW) | W*a_src | W*a_dst],
//                  bc = b*blkdiag(mlW) + mlb  (per stage, exact fp32) ----------------
template<int F_>
__device__ inline void combine_body(const float* __restrict__ w, const float* __restrict__ mlw,
                                    const float* __restrict__ as_, const float* __restrict__ ad,
                                    const float* __restrict__ b, const float* __restrict__ mlb,
                                    float* __restrict__ wc, float* __restrict__ bc,
                                    int K_, int lb) {
    constexpr int NC = 3 * F_ + 6;
    constexpr int JG = 128 / F_;   // row-groups (2 for F=64, 1 for F=128)
    constexpr int RG = 8 / JG;     // rows per thread
    int h = lb % 3, kb = lb / 3;
    int k0 = kb * 8, KS = min(8, K_ - k0);
    int tid = threadIdx.x;
    int j = tid % F_, rg = tid / F_;
    __shared__ float ws[8][F_];
    __shared__ float ms[32][F_];
    __shared__ float bav[3][F_];
    for (int idx = tid; idx < 8 * F_; idx += 128) {
        int r = idx / F_, f = idx % F_;
        ws[r][f] = (r < KS) ? w[(size_t)(k0 + r) * (3 * F_) + h * F_ + f] : 0.f;
    }
    for (int f = tid; f < F_; f += 128) {
        bav[0][f] = b[h * F_ + f];
        bav[1][f] = as_[h * F_ + f];
        bav[2][f] = ad[h * F_ + f];
    }
    __syncthreads();
    const float* mh = mlw + (size_t)h * F_ * F_;
    float acc[RG] = {};
    float bacc = 0.f;
    for (int f0 = 0; f0 < F_; f0 += 32) {
        for (int idx = tid; idx < 32 * F_; idx += 128) {
            int u = idx / F_, jj = idx % F_;
            ms[u][jj] = mh[(size_t)(f0 + u) * F_ + jj];
        }
        __syncthreads();
#pragma unroll
        for (int u = 0; u < 32; u++) {
            float m = ms[u][j];
#pragma unroll
            for (int r = 0; r < RG; r++)
                acc[r] += ws[rg * RG + r][f0 + u] * m;
            if (rg == 0) bacc += bav[0][f0 + u] * m;
        }
        __syncthreads();
    }
#pragma unroll
    for (int r = 0; r < RG; r++) {
        int k = k0 + rg * RG + r;
        if (k < K_) wc[(size_t)k * NC + h * F_ + j] = acc[r];
    }
    if (kb == 0 && rg == 0)
        atomicAdd(&bc[j], bacc + (h == 0 ? mlb[j] : 0.f));
    // score columns: threads (r, src/dst) from staged w-slab (LDS, unrolled)
    if (tid < 16) {
        int r = tid >> 1, sc = tid & 1;
        if (r < KS) {
            float s = 0.f;
#pragma unroll
            for (int f = 0; f < F_; f++) s += ws[r][f] * bav[1 + sc][f];
            wc[(size_t)(k0 + r) * NC + 3 * F_ + sc * 3 + h] = s;
        }
    }
}

struct C64 {
    const float *w[3], *mlw[3], *as_[3], *ad[3], *b[3], *mlb[3];
    float *wc[3], *bc[3];
    int K[3], t0[3];
};
__global__ __launch_bounds__(128)
void k_combine64(C64 a) {
    int bt = blockIdx.x, si = 0;
#pragma unroll
    for (int i = 1; i < 3; i++) if (bt >= a.t0[i]) si = i;
    combine_body<64>(a.w[si], a.mlw[si], a.as_[si], a.ad[si], a.b[si], a.mlb[si],
                     a.wc[si], a.bc[si], a.K[si], bt - a.t0[si]);
}
__global__ __launch_bounds__(128)
void k_combine128(const float* w, const float* mlw, const float* as_, const float* ad,
                  const float* b, const float* mlb, float* wc, float* bc, int K_) {
    combine_body<128>(w, mlw, as_, ad, b, mlb, wc, bc, K_, blockIdx.x);
}

// ---------------- tw1: z = [x|pos] @ Wc1, exact fp32 (K=6, N=198) ----------------
// NOTE: z aliases the dist/key region -> must run AFTER stage-1 nbr is built.
__global__ void k_tw1(const float* __restrict__ x, const float* __restrict__ pos,
                      const float* __restrict__ wc, float* __restrict__ z) {
    int t = blockIdx.x * blockDim.x + threadIdx.x;
    if (t >= NPTS * 198) return;
    int n = t / 198, j = t % 198;
    float acc = 0.f;
#pragma unroll
    for (int c = 0; c < 3; c++) {
        acc += x[n * 3 + c] * wc[c * 198 + j];
        acc += pos[n * 3 + c] * wc[(3 + c) * 198 + j];
    }
    z[(size_t)n * LDZ + j] = acc;
}

// ---------------- fused weight transpose + split (MFMA weights, one launch) ----------
struct WArgs {
    const float* src[NSEG];
    ushort_t* dst[NSEG];
    int K[NSEG], N[NSEG], Kp[NSEG], t0[NSEG];
};
__global__ void k_wsplit_all(WArgs a) {
    int bt = blockIdx.x;
    int si = 0;
#pragma unroll
    for (int i = 1; i < NSEG; i++) if (bt >= a.t0[i]) si = i;
    int t = bt - a.t0[si];
    int K_ = a.K[si], N_ = a.N[si], Kp = a.Kp[si];
    const float* src = a.src[si];
    ushort_t* dh = a.dst[si];
    ushort_t* dl = dh + (size_t)Kp * N_;
    int tX = (N_ + 31) >> 5;
    int k0 = (t / tX) * 32, n0 = (t % tX) * 32;
    __shared__ float tt[32][33];
    int c = threadIdx.x & 31, r8 = threadIdx.x >> 5;
#pragma unroll
    for (int i = 0; i < 4; i++) {
        int r = r8 + i * 8;
        int k = k0 + r, n = n0 + c;
        tt[r][c] = (k < K_ && n < N_) ? src[(size_t)k * N_ + n] : 0.f;
    }
    __syncthreads();
#pragma unroll
    for (int i = 0; i < 4; i++) {
        int r = r8 + i * 8;
        int n = n0 + r, k = k0 + c;
        if (n < N_) {
            float v = tt[c][r];
            ushort_t h, l; split2(v, h, l);
            dh[(size_t)n * Kp + k] = h;
            dl[(size_t)n * Kp + k] = l;
        }
    }
}

// -------- pure-bf16 MFMA GEMM, software-pipelined; fusable epilogues:
//   lsm: log_softmax over Ndim cols;  gmax: column-max (no C write) --------
template<int MT, int NT>
__global__ __launch_bounds__(256)
void k_mgemm1(const ushort_t* __restrict__ A, int lda,
              const ushort_t* __restrict__ W, int ldw,
              float* __restrict__ Cf, int ldc,
              ushort_t* __restrict__ Ch, int ldh,
              int Ndim, int K,
              const float* __restrict__ bias1, const float* __restrict__ bias2,
              int relu, int lsm, uint_t* __restrict__ gmax) {
    constexpr int MTW = MT / 64;
    constexpr int NTT = NT / 16;
    __shared__ ushort_t As[2][MT * 40];
    __shared__ ushort_t Bs[2][NT * 40];
    __shared__ uint_t smax[NT];
    int tid = threadIdx.x;
    int w = tid >> 6, lane = tid & 63;
    int quad = lane >> 4, l16 = lane & 15;
    int m0 = blockIdx.x * MT, n0 = blockIdx.y * NT;
    uint4_t pa[MT / 64], pb[NT / 64];
    auto prefetch = [&](int k0) {
#pragma unroll
        for (int rep = 0; rep < MT / 64; rep++) {
            int idx = tid + rep * 256;
            int row = idx >> 2, q = idx & 3;
            pa[rep] = *(const uint4_t*)(A + (size_t)(m0 + row) * lda + k0 + q * 8);
        }
#pragma unroll
        for (int rep = 0; rep < NT / 64; rep++) {
            int idx = tid + rep * 256;
            int row = idx >> 2, q = idx & 3;
            uint4_t v = {0, 0, 0, 0};
            if (n0 + row < Ndim) v = *(const uint4_t*)(W + (size_t)(n0 + row) * ldw + k0 + q * 8);
            pb[rep] = v;
        }
    };
    auto stage = [&](int buf) {
#pragma unroll
        for (int rep = 0; rep < MT / 64; rep++) {
            int idx = tid + rep * 256;
            int row = idx >> 2, q = idx & 3;
            *(uint4_t*)&As[buf][row * 40 + q * 8] = pa[rep];
        }
#pragma unroll
        for (int rep = 0; rep < NT / 64; rep++) {
            int idx = tid + rep * 256;
            int row = idx >> 2, q = idx & 3;
            *(uint4_t*)&Bs[buf][row * 40 + q * 8] = pb[rep];
        }
    };
    if (gmax) {
        for (int idx = tid; idx < NT; idx += 256) smax[idx] = 0u;
    }
    floatx4 acc[MTW][NTT] = {};
    prefetch(0);
    stage(0);
    __syncthreads();
    int cur = 0;
    for (int k0 = 0; k0 < K; k0 += 32) {
        bool more = (k0 + 32 < K);
        if (more) prefetch(k0 + 32);
        short8 ah[MTW];
#pragma unroll
        for (int mt = 0; mt < MTW; mt++) {
            int r = w * (MT / 4) + mt * 16 + l16;
            ah[mt] = *(short8*)&As[cur][r * 40 + quad * 8];
        }
#pragma unroll
        for (int nt = 0; nt < NTT; nt++) {
            int r = nt * 16 + l16;
            short8 bh = *(short8*)&Bs[cur][r * 40 + quad * 8];
#pragma unroll
            for (int mt = 0; mt < MTW; mt++)
                acc[mt][nt] = __builtin_amdgcn_mfma_f32_16x16x32_bf16(ah[mt], bh, acc[mt][nt], 0, 0, 0);
        }
        if (more) stage(cur ^ 1);
        __syncthreads();
        cur ^= 1;
    }
    if (lsm) {
#pragma unroll
        for (int mt = 0; mt < MTW; mt++) {
#pragma unroll
            for (int r = 0; r < 4; r++) {
                float vv[NTT];
                float mrow = -3e38f;
#pragma unroll
                for (int nt = 0; nt < NTT; nt++) {
                    int n = n0 + nt * 16 + l16;
                    float val = (n < Ndim) ? acc[mt][nt][r] + bias1[n] : -3e38f;
                    vv[nt] = val;
                    mrow = fmaxf(mrow, val);
                }
#pragma unroll
                for (int off = 8; off >= 1; off >>= 1)
                    mrow = fmaxf(mrow, __shfl_xor(mrow, off, 64));
                float s = 0.f;
#pragma unroll
                for (int nt = 0; nt < NTT; nt++)
                    if (vv[nt] > -1e38f) s += expf(vv[nt] - mrow);
#pragma unroll
                for (int off = 8; off >= 1; off >>= 1)
                    s += __shfl_xor(s, off, 64);
                float lse = mrow + logf(s);
                int m = m0 + w * (MT / 4) + mt * 16 + quad * 4 + r;
#pragma unroll
                for (int nt = 0; nt < NTT; nt++) {
                    int n = n0 + nt * 16 + l16;
                    if (n < Ndim) Cf[(size_t)m * ldc + n] = vv[nt] - lse;
                }
            }
        }
        return;
    }
    if (gmax) {
#pragma unroll
        for (int mt = 0; mt < MTW; mt++) {
#pragma unroll
            for (int nt = 0; nt < NTT; nt++) {
#pragma unroll
                for (int r = 0; r < 4; r++) {
                    float v = acc[mt][nt][r] + bias1[nt * 16 + l16 + n0];
                    atomicMax(&smax[nt * 16 + l16], fenc(v));
                }
            }
        }
        __syncthreads();
        for (int idx = tid; idx < NT; idx += 256)
            atomicMax(&gmax[n0 + idx], smax[idx]);
        return;
    }
#pragma unroll
    for (int mt = 0; mt < MTW; mt++) {
#pragma unroll
        for (int nt = 0; nt < NTT; nt++) {
#pragma unroll
            for (int r = 0; r < 4; r++) {
                int m = m0 + w * (MT / 4) + mt * 16 + quad * 4 + r;
                int n = n0 + nt * 16 + l16;
                if (n < Ndim) {
                    float v = acc[mt][nt][r];
                    if (bias1) v += bias1[n];
                    if (bias2) v += bias2[n];
                    if (relu && v < 0.f) v = 0.f;
                    if (Cf) Cf[(size_t)m * ldc + n] = v;
                    if (Ch) Ch[(size_t)m * ldh + n] = f2bs(v);
                }
            }
        }
    }
}

// ---------------- split-bf16 (3-term) MFMA GEMM ----------------
__global__ __launch_bounds__(256)
void k_mgemm3(const ushort_t* __restrict__ Ah, const ushort_t* __restrict__ Al, int lda,
              const ushort_t* __restrict__ Wh, const ushort_t* __restrict__ Wl, int ldw,
              float* __restrict__ Cf, int ldc,
              int Ndim, int K) {
    constexpr int NTT = 4;
    __shared__ ushort_t AsH[64 * 40], BsH[64 * 40], AsL[64 * 40], BsL[64 * 40];
    int tid = threadIdx.x;
    int w = tid >> 6, lane = tid & 63;
    int quad = lane >> 4, l16 = lane & 15;
    int m0 = blockIdx.y * 64, n0 = blockIdx.x * 64;
    floatx4 acc[NTT] = {};
    for (int k0 = 0; k0 < K; k0 += 32) {
        {
            int row = tid >> 2, q = tid & 3;
            size_t go = (size_t)(m0 + row) * lda + k0 + q * 8;
            *(uint4_t*)&AsH[row * 40 + q * 8] = *(const uint4_t*)(Ah + go);
            *(uint4_t*)&AsL[row * 40 + q * 8] = *(const uint4_t*)(Al + go);
            uint4_t vh = {0, 0, 0, 0}, vl = {0, 0, 0, 0};
            size_t gw = (size_t)(n0 + row) * ldw + k0 + q * 8;
            if (n0 + row < Ndim) { vh = *(const uint4_t*)(Wh + gw); vl = *(const uint4_t*)(Wl + gw); }
            *(uint4_t*)&BsH[row * 40 + q * 8] = vh;
            *(uint4_t*)&BsL[row * 40 + q * 8] = vl;
        }
        __syncthreads();
        short8 ah, al;
        {
            int r = w * 16 + l16;
            ah = *(short8*)&AsH[r * 40 + quad * 8];
            al = *(short8*)&AsL[r * 40 + quad * 8];
        }
#pragma unroll
        for (int nt = 0; nt < NTT; nt++) {
            int r = nt * 16 + l16;
            short8 bh = *(short8*)&BsH[r * 40 + quad * 8];
            short8 bl = *(short8*)&BsL[r * 40 + quad * 8];
            acc[nt] = __builtin_amdgcn_mfma_f32_16x16x32_bf16(ah, bh, acc[nt], 0, 0, 0);
            acc[nt] = __builtin_amdgcn_mfma_f32_16x16x32_bf16(ah, bl, acc[nt], 0, 0, 0);
            acc[nt] = __builtin_amdgcn_mfma_f32_16x16x32_bf16(al, bh, acc[nt], 0, 0, 0);
        }
        __syncthreads();
    }
#pragma unroll
    for (int nt = 0; nt < NTT; nt++) {
#pragma unroll
        for (int r = 0; r < 4; r++) {
            int m = m0 + w * 16 + quad * 4 + r;
            int n = n0 + nt * 16 + l16;
            if (n < Ndim) Cf[(size_t)m * ldc + n] = acc[nt][r];
        }
    }
}

// ---------------- split-bf16 MFMA pairwise distances -> packed sort keys -----------
// keys stored through cache (L3-resident for the immediately-following k_topk read).
__global__ __launch_bounds__(256)
void k_mdist(const ushort_t* __restrict__ Lh, const ushort_t* __restrict__ Ll,
             int co, int C, uint_t* __restrict__ keys) {
    __shared__ ushort_t AsH[128 * 40], AsL[128 * 40], BsH[64 * 40], BsL[64 * 40];
    __shared__ float sqa[128], sqb[64];
    int tid = threadIdx.x;
    int w = tid >> 6, lane = tid & 63;
    int quad = lane >> 4, l16 = lane & 15;
    int b = blockIdx.z, cb = b * PP;
    int i0 = blockIdx.y * 128, j0 = blockIdx.x * 64;
    floatx4 acc[2][4] = {};
    float sacc = 0.f;
    for (int k0 = 0; k0 < C; k0 += 32) {
#pragma unroll
        for (int rep = 0; rep < 8; rep++) {
            int d = tid + rep * 256;
            int row = d >> 4, c2 = d & 15;
            size_t gi = ((size_t)(cb + i0 + row) * LDH + co + k0 + c2 * 2) >> 1;
            *(uint_t*)&AsH[row * 40 + c2 * 2] = ((const uint_t*)Lh)[gi];
            *(uint_t*)&AsL[row * 40 + c2 * 2] = ((const uint_t*)Ll)[gi];
        }
#pragma unroll
        for (int rep = 0; rep < 4; rep++) {
            int d = tid + rep * 256;
            int row = d >> 4, c2 = d & 15;
            size_t gi = ((size_t)(cb + j0 + row) * LDH + co + k0 + c2 * 2) >> 1;
            *(uint_t*)&BsH[row * 40 + c2 * 2] = ((const uint_t*)Lh)[gi];
            *(uint_t*)&BsL[row * 40 + c2 * 2] = ((const uint_t*)Ll)[gi];
        }
        __syncthreads();
        if (tid < 128) {
#pragma unroll
            for (int kk = 0; kk < 16; kk++) {
                uint_t ph = *(uint_t*)&AsH[tid * 40 + kk * 2];
                uint_t pl = *(uint_t*)&AsL[tid * 40 + kk * 2];
                float v0 = bs2f((ushort_t)(ph & 0xFFFFu)) + bs2f((ushort_t)(pl & 0xFFFFu));
                sacc += v0 * v0;
                float v1 = bs2f((ushort_t)(ph >> 16)) + bs2f((ushort_t)(pl >> 16));
                sacc += v1 * v1;
            }
        } else if (tid < 192) {
            int row = tid - 128;
#pragma unroll
            for (int kk = 0; kk < 16; kk++) {
                uint_t ph = *(uint_t*)&BsH[row * 40 + kk * 2];
                uint_t pl = *(uint_t*)&BsL[row * 40 + kk * 2];
                float v0 = bs2f((ushort_t)(ph & 0xFFFFu)) + bs2f((ushort_t)(pl & 0xFFFFu));
                sacc += v0 * v0;
                float v1 = bs2f((ushort_t)(ph >> 16)) + bs2f((ushort_t)(pl >> 16));
                sacc += v1 * v1;
            }
        }
        short8 ah[2], al[2];
#pragma unroll
        for (int mt = 0; mt < 2; mt++) {
            int r = w * 32 + mt * 16 + l16;
            ah[mt] = *(short8*)&AsH[r * 40 + quad * 8];
            al[mt] = *(short8*)&AsL[r * 40 + quad * 8];
        }
#pragma unroll
        for (int nt = 0; nt < 4; nt++) {
            int r = nt * 16 + l16;
            short8 bh = *(short8*)&BsH[r * 40 + quad * 8];
            short8 bl = *(short8*)&BsL[r * 40 + quad * 8];
#pragma unroll
            for (int mt = 0; mt < 2; mt++) {
                acc[mt][nt] = __builtin_amdgcn_mfma_f32_16x16x32_bf16(ah[mt], bh, acc[mt][nt], 0, 0, 0);
                acc[mt][nt] = __builtin_amdgcn_mfma_f32_16x16x32_bf16(ah[mt], bl, acc[mt][nt], 0, 0, 0);
                acc[mt][nt] = __builtin_amdgcn_mfma_f32_16x16x32_bf16(al[mt], bh, acc[mt][nt], 0, 0, 0);
            }
        }
        __syncthreads();
    }
    if (tid < 128) sqa[tid] = sacc;
    else if (tid < 192) sqb[tid - 128] = sacc;
    __syncthreads();
#pragma unroll
    for (int mt = 0; mt < 2; mt++) {
#pragma unroll
        for (int nt = 0; nt < 4; nt++) {
#pragma unroll
            for (int r = 0; r < 4; r++) {
                int li = w * 32 + mt * 16 + quad * 4 + r;
                int lj = nt * 16 + l16;
                int il = i0 + li, jl = j0 + lj;
                float dd = sqa[li] + sqb[lj] - 2.f * acc[mt][nt][r];
                dd = (il == jl) ? 3e9f : fmaxf(dd, 0.f);
                uint_t key = (__float_as_uint(dd) & 0xFFFFF800u) | (uint_t)jl;
                keys[(size_t)(cb + il) * PP + jl] = key;
            }
        }
    }
}

// ---------------- top-30 smallest per row via packed u32 keys ----------------
__global__ __launch_bounds__(256)
void k_topk(const uint_t* __restrict__ keys, int* __restrict__ nbr) {
    int r = blockIdx.x * 4 + (threadIdx.x >> 6);
    int lane = threadIdx.x & 63;
    int base = (r / PP) * PP;
    const uint_t* row = keys + (size_t)r * PP;
    uint_t v[32];
#pragma unroll
    for (int j = 0; j < 8; j++)
        *(uint4_t*)&v[j * 4] = *(const uint4_t*)(row + lane * 4 + j * 256);
    uint_t g[8];
#pragma unroll
    for (int j = 0; j < 8; j++)
        g[j] = min(min(v[j * 4], v[j * 4 + 1]), min(v[j * 4 + 2], v[j * 4 + 3]));
    uint_t lv = g[0];
#pragma unroll
    for (int j = 1; j < 8; j++) lv = min(lv, g[j]);
    for (int sel = 0; sel < KNN; sel++) {
        uint_t bk = lv;
#pragma unroll
        for (int off = 32; off > 0; off >>= 1)
            bk = min(bk, (uint_t)__shfl_xor((int)bk, off, 64));
        uint_t bks = __builtin_amdgcn_readfirstlane(bk);
        if (lane == 0) nbr[r * KTOT + sel] = base + (int)(bks & 0x7FFu);
        int grp = (int)((bks & 0x7FFu) >> 8);
#pragma unroll
        for (int jj = 0; jj < 8; jj++)
            if (grp == jj) {
#pragma unroll
                for (int t = 0; t < 4; t++)
                    v[jj * 4 + t] = (v[jj * 4 + t] == bks) ? 0xFFFFFFFFu : v[jj * 4 + t];
                g[jj] = min(min(v[jj * 4], v[jj * 4 + 1]), min(v[jj * 4 + 2], v[jj * 4 + 3]));
            }
        lv = g[0];
#pragma unroll
        for (int j = 1; j < 8; j++) lv = min(lv, g[j]);
    }
    if (lane == 0) nbr[r * KTOT + KNN] = r;
}

// ---------------- GAT edge-softmax + aggregate, fp32 z (stages 1-2) ----------------
// z row: [3F proj | 3 src-scores | 3 dst-scores].  NN nodes/block, 192 threads.
template<int F, int NN>
__global__ __launch_bounds__(192)
void k_gat2(const float* __restrict__ z, int ldz,
            const int* __restrict__ nbr,
            const float* __restrict__ bc,
            ushort_t* __restrict__ dh, ushort_t* __restrict__ dl) {
    constexpr int TPN = 3 * F / 4;   // threads per node in aggregate (48 or 96)
    __shared__ int srcs[NN][KTOT];
    __shared__ float alpha[NN][96];
    __shared__ float part[NN][2][F];
    int tid = threadIdx.x;
    if (tid < NN * KTOT) {
        int u = tid / KTOT, k = tid % KTOT;
        int t = blockIdx.x * NN + u;
        int node = (t & 3) * PP + (t >> 2);
        srcs[u][k] = nbr[node * KTOT + k];
    }
    __syncthreads();
#pragma unroll
    for (int u2 = 0; u2 < NN; u2 += 2) {
        int u = u2 + tid / 96;       // 2 nodes per 192-thread pass; 32-lane aligned groups
        int r = tid % 96, h = r >> 5, k = r & 31;
        int t = blockIdx.x * NN + u;
        int node = (t & 3) * PP + (t >> 2);
        float e = -3e38f;
        if (k < KTOT) {
            float sv = z[(size_t)srcs[u][k] * ldz + 3 * F + h];
            float tv = z[(size_t)node * ldz + 3 * F + 3 + h];
            e = sv + tv;
            if (e < 0.f) e *= 0.2f;
        }
        float m = e;
#pragma unroll
        for (int off = 16; off >= 1; off >>= 1)
            m = fmaxf(m, __shfl_xor(m, off, 32));
        float ex = (k < KTOT) ? expf(e - m) : 0.f;
        float s = ex;
#pragma unroll
        for (int off = 16; off >= 1; off >>= 1)
            s += __shfl_xor(s, off, 32);
        alpha[u][h * 32 + k] = ex / s;
    }
    __syncthreads();
    // aggregate: thread -> (u, h, j-quad); float4 gathers, 2 vector accumulators
    {
        int u = tid / TPN, r = tid % TPN;
        int h = r / (F / 4), jq = r % (F / 4);
        const float* zb = z + h * F + jq * 4;
        floatx4 a0 = {0.f, 0.f, 0.f, 0.f}, a1 = {0.f, 0.f, 0.f, 0.f};
#pragma unroll
        for (int k = 0; k < KTOT; k += 2) {
            float a = alpha[u][h * 32 + k];
            floatx4 p = *(const floatx4*)(zb + (size_t)srcs[u][k] * ldz);
            a0 += p * a;
            if (k + 1 < KTOT) {
                float a2 = alpha[u][h * 32 + k + 1];
                floatx4 p2 = *(const floatx4*)(zb + (size_t)srcs[u][k + 1] * ldz);
                a1 += p2 * a2;
            }
        }
        floatx4 av = a0 + a1;
        if (h > 0)
            *(floatx4*)&part[u][h - 1][jq * 4] = av;
        __syncthreads();
        if (h == 0) {
            int t = blockIdx.x * NN + u;
            int node = (t & 3) * PP + (t >> 2);
            int j0 = jq * 4;
            floatx4 p0 = *(const floatx4*)&part[u][0][j0];
            floatx4 p1 = *(const floatx4*)&part[u][1][j0];
            floatx4 bcv = *(const floatx4*)&bc[j0];
            floatx4 v = av + p0 + p1 + bcv;
            ushort_t hh[4], ll[4];
#pragma unroll
            for (int q = 0; q < 4; q++) split2(v[q], hh[q], ll[q]);
            *(uint_t*)&dh[(size_t)node * LDH + j0] = (uint_t)hh[0] | ((uint_t)hh[1] << 16);
            *(uint_t*)&dh[(size_t)node * LDH + j0 + 2] = (uint_t)hh[2] | ((uint_t)hh[3] << 16);
            if (dl) {
                *(uint_t*)&dl[(size_t)node * LDH + j0] = (uint_t)ll[0] | ((uint_t)ll[1] << 16);
                *(uint_t*)&dl[(size_t)node * LDH + j0 + 2] = (uint_t)ll[2] | ((uint_t)ll[3] << 16);
            }
        }
    }
}

// ---------------- GAT edge-softmax + aggregate, bf16 z (stages 3-4) ----------------
// z stored bf16 -> half the gather bytes.  Thread owns (node, head, j-oct):
// short8 gathers (16B = 8 cols), 8 independent FMA chains.  All 192 threads active.
template<int F, int NN>
__global__ __launch_bounds__(192)
void k_gat2b(const ushort_t* __restrict__ z, int ldz,
             const int* __restrict__ nbr,
             const float* __restrict__ bc,
             ushort_t* __restrict__ dh) {
    constexpr int TPN = 3 * F / 8;   // 24 (F=64, NN=8) or 48 (F=128, NN=4)
    __shared__ int srcs[NN][KTOT];
    __shared__ float alpha[NN][96];
    __shared__ float part[NN][2][F];
    int tid = threadIdx.x;
    for (int idx = tid; idx < NN * KTOT; idx += 192) {
        int u = idx / KTOT, k = idx % KTOT;
        int t = blockIdx.x * NN + u;
        int node = (t & 3) * PP + (t >> 2);
        srcs[u][k] = nbr[node * KTOT + k];
    }
    __syncthreads();
#pragma unroll
    for (int u2 = 0; u2 < NN; u2 += 2) {
        int u = u2 + tid / 96;
        int r = tid % 96, h = r >> 5, k = r & 31;
        int t = blockIdx.x * NN + u;
        int node = (t & 3) * PP + (t >> 2);
        float e = -3e38f;
        if (k < KTOT) {
            float sv = bs2f(z[(size_t)srcs[u][k] * ldz + 3 * F + h]);
            float tv = bs2f(z[(size_t)node * ldz + 3 * F + 3 + h]);
            e = sv + tv;
            if (e < 0.f) e *= 0.2f;
        }
        float m = e;
#pragma unroll
        for (int off = 16; off >= 1; off >>= 1)
            m = fmaxf(m, __shfl_xor(m, off, 32));
        float ex = (k < KTOT) ? expf(e - m) : 0.f;
        float s = ex;
#pragma unroll
        for (int off = 16; off >= 1; off >>= 1)
            s += __shfl_xor(s, off, 32);
        alpha[u][h * 32 + k] = ex / s;
    }
    __syncthreads();
    {
        int u = tid / TPN, r = tid % TPN;
        int h = r / (F / 8), jo = r % (F / 8);
        const ushort_t* zb = z + h * F + jo * 8;
        float a[8] = {};
        for (int k = 0; k < KTOT; k++) {
            float al = alpha[u][h * 32 + k];
            short8 v = *(const short8*)(zb + (size_t)srcs[u][k] * ldz);
#pragma unroll
            for (int q = 0; q < 8; q++)
                a[q] += al * bs2f((ushort_t)v[q]);
        }
        if (h > 0) {
#pragma unroll
            for (int q = 0; q < 8; q++) part[u][h - 1][jo * 8 + q] = a[q];
        }
        __syncthreads();
        if (h == 0) {
            int t = blockIdx.x * NN + u;
            int node = (t & 3) * PP + (t >> 2);
            int j0 = jo * 8;
#pragma unroll
            for (int q2 = 0; q2 < 4; q2++) {
                float v0 = a[q2 * 2] + part[u][0][j0 + q2 * 2] + part[u][1][j0 + q2 * 2] + bc[j0 + q2 * 2];
                float v1 = a[q2 * 2 + 1] + part[u][0][j0 + q2 * 2 + 1] + part[u][1][j0 + q2 * 2 + 1] + bc[j0 + q2 * 2 + 1];
                *(uint_t*)&dh[(size_t)node * LDH + j0 + q2 * 2] =
                    (uint_t)f2bs(v0) | ((uint_t)f2bs(v1) << 16);
            }
        }
    }
}

// ---------------- gproj: decode fused column max + split-K matmul ----------------
__global__ void k_gproj(const uint_t* __restrict__ genc,
                        const float* __restrict__ mw1,
                        const float* __restrict__ mb1,
                        float* __restrict__ gproj) {
    __shared__ float gs[128];
    int kb = blockIdx.x;           // 8 blocks x 128 k
    int t = threadIdx.x;           // 256
    if (t < 128) gs[t] = fdec(genc[kb * 128 + t]);
    __syncthreads();
    float acc = (kb == 0) ? mb1[t] : 0.f;
    for (int k = 0; k < 128; k++)
        acc += gs[k] * mw1[(size_t)(326 + kb * 128 + k) * 256 + t];
    atomicAdd(&gproj[t], acc);
}

// ---------------- host side ----------------
struct WT { ushort_t *h, *l; int kp; };

extern "C" void kernel_launch(void* const* d_in, const int* in_sizes, int n_in,
                              void* d_out, int out_size, void* d_ws, size_t ws_size,
                              hipStream_t stream) {
    (void)in_sizes; (void)n_in; (void)out_size; (void)ws_size;
    const float* x    = (const float*)d_in[0];
    const float* pos  = (const float*)d_in[1];
    const float* w1   = (const float*)d_in[3];
    const float* as1  = (const float*)d_in[4];
    const float* ad1  = (const float*)d_in[5];
    const float* b1   = (const float*)d_in[6];
    const float* ml1w = (const float*)d_in[7];
    const float* ml1b = (const float*)d_in[8];
    const float* w2   = (const float*)d_in[9];
    const float* as2  = (const float*)d_in[10];
    const float* ad2  = (const float*)d_in[11];
    const float* b2   = (const float*)d_in[12];
    const float* ml2w = (const float*)d_in[13];
    const float* ml2b = (const float*)d_in[14];
    const float* w3   = (const float*)d_in[15];
    const float* as3  = (const float*)d_in[16];
    const float* ad3  = (const float*)d_in[17];
    const float* b3   = (const float*)d_in[18];
    const float* ml3w = (const float*)d_in[19];
    const float* ml3b = (const float*)d_in[20];
    const float* w4   = (const float*)d_in[21];
    const float* as4  = (const float*)d_in[22];
    const float* ad4  = (const float*)d_in[23];
    const float* b4   = (const float*)d_in[24];
    const float* ml4w = (const float*)d_in[25];
    const float* ml4b = (const float*)d_in[26];
    const float* few1 = (const float*)d_in[27];
    const float* feb1 = (const float*)d_in[28];
    const float* few2 = (const float*)d_in[29];
    const float* feb2 = (const float*)d_in[30];
    const float* mw1  = (const float*)d_in[31];
    const float* mb1  = (const float*)d_in[32];
    const float* mw2  = (const float*)d_in[33];
    const float* mb2  = (const float*)d_in[34];
    const float* mw3  = (const float*)d_in[35];
    const float* mb3  = (const float*)d_in[36];
    const float* mw4  = (const float*)d_in[37];
    const float* mb4  = (const float*)d_in[38];

    float* Wb = (float*)d_ws;
    size_t off = 0;
    auto alloc = [&](size_t n) { float* p = Wb + off; off += (n + 63) & ~(size_t)63; return p; };

    float*    dist = alloc((size_t)NPTS * PP);                  // 67 MB aliased region
    ushort_t* l4h  = (ushort_t*)alloc((size_t)NPTS * LDH / 2);
    ushort_t* l4l  = (ushort_t*)alloc((size_t)NPTS * LDH / 2);
    // genc|gproj|bcp contiguous -> single memset
    uint_t* genc = (uint_t*)alloc(1024);                        // encoded col maxima
    float* gproj = alloc(256);
    float* bcp = alloc(320);                                    // bc1|bc2|bc3|bc4
    float* bc1 = bcp, *bc2 = bcp + 64, *bc3 = bcp + 128, *bc4 = bcp + 192;
    int*   nbr   = (int*)alloc((size_t)NPTS * KTOT);
    ushort_t* wtpool = (ushort_t*)alloc(1742336);
    float* wc1 = alloc(6 * 198);
    float* wc2 = alloc(70 * 198);
    float* wc3 = alloc(134 * 198);
    float* wc4 = alloc(198 * 390);

    // aliases inside dist region (disjoint lifetimes):
    //   dkey lives between k_mdist and k_topk (stages 2-3); z/zb written after nbr
    //   consumed keys; hah/bAh/bBh/bCh live in the fe/head phase only.
    char* d0 = (char*)dist;
    uint_t*   dkey = (uint_t*)dist;
    float*    z    = dist;
    ushort_t* zb   = (ushort_t*)dist;                           // bf16 z (stages 3-4)
    ushort_t* hah  = (ushort_t*)d0;                             // fe1 out hi (16.8MB)
    ushort_t* bBh  = (ushort_t*)(d0 + (size_t)NPTS * 1024 * 2); // mw2 out hi
    ushort_t* bAh = (ushort_t*)d0;                              // mw1 out hi (hah dead)
    ushort_t* bCh = (ushort_t*)d0;                              // mw3 out hi (bAh dead)

    // ---- zero link4 planes + accumulators ----
    hipMemsetAsync(l4h, 0, (size_t)NPTS * LDH * 4, stream);     // covers hi+lo (contiguous)
    hipMemsetAsync(genc, 0, (1024 + 256 + 320) * 4, stream);    // genc|gproj|bcp

    // ---- combined GAT weights (ml-proj + scores folded into producing GEMM) ----
    {
        C64 ca;
        const float* ws_[3] = {w1, w2, w3};
        const float* mlws[3] = {ml1w, ml2w, ml3w};
        const float* ass[3] = {as1, as2, as3};
        const float* ads[3] = {ad1, ad2, ad3};
        const float* bs_[3] = {b1, b2, b3};
        const float* mlbs[3] = {ml1b, ml2b, ml3b};
        float* wcs[3] = {wc1, wc2, wc3};
        float* bcs[3] = {bc1, bc2, bc3};
        int Ks[3] = {6, 70, 134};
        int t = 0;
        for (int i = 0; i < 3; i++) {
            ca.w[i] = ws_[i]; ca.mlw[i] = mlws[i]; ca.as_[i] = ass[i]; ca.ad[i] = ads[i];
            ca.b[i] = bs_[i]; ca.mlb[i] = mlbs[i]; ca.wc[i] = wcs[i]; ca.bc[i] = bcs[i];
            ca.K[i] = Ks[i]; ca.t0[i] = t;
            t += ((Ks[i] + 7) / 8) * 3;
        }
        k_combine64<<<t, 128, 0, stream>>>(ca);
        k_combine128<<<25 * 3, 128, 0, stream>>>(w4, ml4w, as4, ad4, b4, ml4b, wc4, bc4, 198);
    }

    // ---- fused weight transpose+split (MFMA weights; combined ones from wc*) ----
    WArgs wa;
    WT wt[NSEG];
    {
        const float* srcs[NSEG] = {wc2, wc3, wc4, few1, few2, mw1, mw2, mw3, mw4};
        int Ks[NSEG] = {70, 134, 198, 326, 1024, 326, 256, 256, 128};
        int Ns[NSEG] = {198, 198, 390, 1024, 1024, 256, 256, 128, 50};
        size_t wo = 0; int tiles = 0;
        for (int i = 0; i < NSEG; i++) {
            int kp = (Ks[i] + 31) & ~31;
            wa.src[i] = srcs[i];
            wa.dst[i] = wtpool + wo;
            wa.K[i] = Ks[i]; wa.N[i] = Ns[i]; wa.Kp[i] = kp;
            wa.t0[i] = tiles;
            wt[i] = { wtpool + wo, wtpool + wo + (size_t)kp * Ns[i], kp };
            wo += (size_t)2 * kp * Ns[i];
            tiles += (kp / 32) * ((Ns[i] + 31) / 32);
        }
        k_wsplit_all<<<tiles, 256, 0, stream>>>(wa);
    }
    WT tw2 = wt[0], tw3 = wt[1], tw4 = wt[2], tfe1 = wt[3], tfe2 = wt[4],
       tmw1 = wt[5], tmw2 = wt[6], tmw3 = wt[7], tmw4 = wt[8];

    auto mg3 = [&](const ushort_t* Ah, const ushort_t* Al, int lda, WT t,
                   float* Cf, int ldc, int Nd, int K) {
        dim3 g((Nd + 63) / 64, NPTS / 64);
        k_mgemm3<<<g, 256, 0, stream>>>(Ah, Al, lda, t.h, t.l, t.kp, Cf, ldc, Nd, K);
    };
    auto mg1 = [&](int MT, int NT, const ushort_t* Ah, int lda, WT t,
                   float* Cf, int ldc, ushort_t* Ch, int ldhh,
                   int Nd, int K, const float* bb1, const float* bb2,
                   int relu, int lsm, uint_t* gmax) {
        dim3 g(NPTS / MT, (Nd + NT - 1) / NT);
        if (MT == 128 && NT == 128)
            k_mgemm1<128, 128><<<g, 256, 0, stream>>>(Ah, lda, t.h, t.kp, Cf, ldc, Ch, ldhh, Nd, K,
                bb1, bb2, relu, lsm, gmax);
        else if (MT == 128)
            k_mgemm1<128, 64><<<g, 256, 0, stream>>>(Ah, lda, t.h, t.kp, Cf, ldc, Ch, ldhh, Nd, K,
                bb1, bb2, relu, lsm, gmax);
        else
            k_mgemm1<64, 64><<<g, 256, 0, stream>>>(Ah, lda, t.h, t.kp, Cf, ldc, Ch, ldhh, Nd, K,
                bb1, bb2, relu, lsm, gmax);
    };

    dim3 dgrid(PP / 64, PP / 128, 4);
    k_build_x0<<<(NPTS * 6 + 255) / 256, 256, 0, stream>>>(x, pos, l4h, l4l);

    // ---- stage 1: fused knn on x0 (C=6, LDS-resident, no key round-trip); gat -> x1 ----
    k_knn6<<<NPTS / 4, 256, 0, stream>>>(x, pos, nbr);
    k_tw1<<<(NPTS * 198 + 255) / 256, 256, 0, stream>>>(x, pos, wc1, z);
    k_gat2<64, 4><<<NPTS / 4, 192, 0, stream>>>(z, LDZ, nbr, bc1, l4h + 6, l4l + 6);

    // ---- stage 2: knn on x1 (C=64); split-bf16 GEMM -> z2 (proj+scores); gat -> x2 ----
    k_mdist<<<dgrid, 256, 0, stream>>>(l4h, l4l, 6, 64, dkey);
    k_topk<<<NPTS / 4, 256, 0, stream>>>(dkey, nbr);
    mg3(l4h, l4l, LDH, tw2, z, LDZ, 198, 70);
    k_gat2<64, 4><<<NPTS / 4, 192, 0, stream>>>(z, LDZ, nbr, bc2, l4h + 70, l4l + 70);

    // ---- stage 3: knn on x2 (C=64); hi-only GEMM -> zb3 (bf16); gat -> x3 (hi only) ----
    k_mdist<<<dgrid, 256, 0, stream>>>(l4h, l4l, 70, 64, dkey);
    k_topk<<<NPTS / 4, 256, 0, stream>>>(dkey, nbr);
    mg1(128, 64, l4h, LDH, tw3, nullptr, 0, zb, LDZB3, 198, 134, nullptr, nullptr, 0, 0, nullptr);
    k_gat2b<64, 8><<<NPTS / 8, 192, 0, stream>>>(zb, LDZB3, nbr, bc3, l4h + 134);

    // ---- stage 4 (reuses stage-3 nbr): GEMM -> zb4 (bf16); gat(F=128) -> x4 (hi only) ----
    mg1(128, 64, l4h, LDH, tw4, nullptr, 0, zb, LDZB4, 390, 198, nullptr, nullptr, 0, 0, nullptr);
    k_gat2b<128, 4><<<NPTS / 4, 192, 0, stream>>>(zb, LDZB4, nbr, bc4, l4h + 198);

    // ---- fe_mlp: fe1 -> bf16 acts; fe2 -> fused global column max (no C write) ----
    mg1(128, 128, l4h, LDH, tfe1, nullptr, 0, hah, 1024, 1024, 326, feb1, nullptr, 1, 0, nullptr);
    mg1(128, 128, hah, 1024, tfe2, nullptr, 0, nullptr, 0, 1024, 1024, feb2, nullptr, 0, 0, genc);
    k_gproj<<<8, 256, 0, stream>>>(genc, mw1, mb1, gproj);

    // ---- head (bf16 tier; mw4 fuses log_softmax and writes d_out) ----
    mg1(128, 64, l4h, LDH, tmw1, nullptr, 0, bAh, 256, 256, 326, nullptr, gproj, 1, 0, nullptr);
    mg1(128, 64, bAh, 256, tmw2, nullptr, 0, bBh, 256, 256, 256, mb2, nullptr, 1, 0, nullptr);
    mg1(64, 64, bBh, 256, tmw3, nullptr, 0, bCh, 128, 128, 256, mb3, nullptr, 1, 0, nullptr);
    mg1(64, 64, bCh, 128, tmw4, (float*)d_out, 50, nullptr, 0, 50, 128, mb4, nullptr, 0, 1, nullptr);
}

// Round 10
// 519.203 us; speedup vs baseline: 1.0595x; 1.0595x over previous
//
#include <hip/hip_runtime.h>
#include <hip/hip_bf16.h>
#include <hip/amd_detail/amd_hip_vector_types.h>

#define NPTS 8192
#define PP 2048
#define KNN 30
#define KTOT 31
#define HEADS 3
#define LDH 352   // padded ld for link4 hi/lo (bf16): >= Kpad32(326), mult of 8
#define NSEG 9
#define LDZ 200   // z ld stages 1-2 (fp32): 198 cols = 192 proj + 3 s + 3 t
#define LDZB3 200 // z ld stage 3 (bf16 ushorts)
#define LDZB4 392 // z ld stage 4 (bf16 ushorts): 390 cols = 384 proj + 3 s + 3 t

typedef __attribute__((ext_vector_type(8))) short short8;
typedef __attribute__((ext_vector_type(4))) float floatx4;
typedef __attribute__((ext_vector_type(4))) unsigned int uint4_t;
typedef unsigned short ushort_t;
typedef unsigned int uint_t;

__device__ inline ushort_t f2bs(float v) {
    __hip_bfloat16 b = __float2bfloat16(v);
    return *reinterpret_cast<ushort_t*>(&b);
}
__device__ inline float bs2f(ushort_t u) {
    __hip_bfloat16 b = *reinterpret_cast<__hip_bfloat16*>(&u);
    return __bfloat162float(b);
}
__device__ inline void split2(float v, ushort_t& h, ushort_t& l) {
    h = f2bs(v);
    l = f2bs(v - bs2f(h));
}
// order-preserving fp32 <-> uint mapping for atomic max
__device__ inline uint_t fenc(float f) {
    uint_t b = __float_as_uint(f);
    return (b & 0x80000000u) ? ~b : (b | 0x80000000u);
}
__device__ inline float fdec(uint_t e) {
    return __uint_as_float((e & 0x80000000u) ? (e & 0x7FFFFFFFu) : ~e);
}

// ---------------- build x0 (hi/lo) into link4 cols 0..5 ----------------
__global__ void k_build_x0(const float* __restrict__ x, const float* __restrict__ pos,
                           ushort_t* __restrict__ lh, ushort_t* __restrict__ ll) {
    int i = blockIdx.x * blockDim.x + threadIdx.x;
    if (i >= NPTS * 6) return;
    int n = i / 6, c = i % 6;
    float v = (c < 3) ? x[n * 3 + c] : pos[n * 3 + (c - 3)];
    ushort_t h, l; split2(v, h, l);
    lh[(size_t)n * LDH + c] = h;
    ll[(size_t)n * LDH + c] = l;
}

// ---------------- combined GAT weights: Wc = [W*blkdiag(mlW) | W*a_src | W*a_dst],
//                  bc = b*blkdiag(mlW) + mlb  (per stage, exact fp32) ----------------
template<int F_>
__device__ inline void combine_body(const float* __restrict__ w, const float* __restrict__ mlw,
                                    const float* __restrict__ as_, const float* __restrict__ ad,
                                    const float* __restrict__ b, const float* __restrict__ mlb,
                                    float* __restrict__ wc, float* __restrict__ bc,
                                    int K_, int lb) {
    constexpr int NC = 3 * F_ + 6;
    constexpr int JG = 128 / F_;   // row-groups (2 for F=64, 1 for F=128)
    constexpr int RG = 8 / JG;     // rows per thread
    int h = lb % 3, kb = lb / 3;
    int k0 = kb * 8, KS = min(8, K_ - k0);
    int tid = threadIdx.x;
    int j = tid % F_, rg = tid / F_;
    __shared__ float ws[8][F_];
    __shared__ float ms[32][F_];
    __shared__ float bav[3][F_];
    for (int idx = tid; idx < 8 * F_; idx += 128) {
        int r = idx / F_, f = idx % F_;
        ws[r][f] = (r < KS) ? w[(size_t)(k0 + r) * (3 * F_) + h * F_ + f] : 0.f;
    }
    for (int f = tid; f < F_; f += 128) {
        bav[0][f] = b[h * F_ + f];
        bav[1][f] = as_[h * F_ + f];
        bav[2][f] = ad[h * F_ + f];
    }
    __syncthreads();
    const float* mh = mlw + (size_t)h * F_ * F_;
    float acc[RG] = {};
    float bacc = 0.f;
    for (int f0 = 0; f0 < F_; f0 += 32) {
        for (int idx = tid; idx < 32 * F_; idx += 128) {
            int u = idx / F_, jj = idx % F_;
            ms[u][jj] = mh[(size_t)(f0 + u) * F_ + jj];
        }
        __syncthreads();
#pragma unroll
        for (int u = 0; u < 32; u++) {
            float m = ms[u][j];
#pragma unroll
            for (int r = 0; r < RG; r++)
                acc[r] += ws[rg * RG + r][f0 + u] * m;
            if (rg == 0) bacc += bav[0][f0 + u] * m;
        }
        __syncthreads();
    }
#pragma unroll
    for (int r = 0; r < RG; r++) {
        int k = k0 + rg * RG + r;
        if (k < K_) wc[(size_t)k * NC + h * F_ + j] = acc[r];
    }
    if (kb == 0 && rg == 0)
        atomicAdd(&bc[j], bacc + (h == 0 ? mlb[j] : 0.f));
    // score columns: threads (r, src/dst) from staged w-slab (LDS, unrolled)
    if (tid < 16) {
        int r = tid >> 1, sc = tid & 1;
        if (r < KS) {
            float s = 0.f;
#pragma unroll
            for (int f = 0; f < F_; f++) s += ws[r][f] * bav[1 + sc][f];
            wc[(size_t)(k0 + r) * NC + 3 * F_ + sc * 3 + h] = s;
        }
    }
}

struct C64 {
    const float *w[3], *mlw[3], *as_[3], *ad[3], *b[3], *mlb[3];
    float *wc[3], *bc[3];
    int K[3], t0[3];
};
__global__ __launch_bounds__(128)
void k_combine64(C64 a) {
    int bt = blockIdx.x, si = 0;
#pragma unroll
    for (int i = 1; i < 3; i++) if (bt >= a.t0[i]) si = i;
    combine_body<64>(a.w[si], a.mlw[si], a.as_[si], a.ad[si], a.b[si], a.mlb[si],
                     a.wc[si], a.bc[si], a.K[si], bt - a.t0[si]);
}
__global__ __launch_bounds__(128)
void k_combine128(const float* w, const float* mlw, const float* as_, const float* ad,
                  const float* b, const float* mlb, float* wc, float* bc, int K_) {
    combine_body<128>(w, mlw, as_, ad, b, mlb, wc, bc, K_, blockIdx.x);
}

// ---------------- tw1: z = [x|pos] @ Wc1, exact fp32 (K=6, N=198) ----------------
// NOTE: z aliases the dist/key region -> must run AFTER k_topk consumed the keys.
__global__ void k_tw1(const float* __restrict__ x, const float* __restrict__ pos,
                      const float* __restrict__ wc, float* __restrict__ z) {
    int t = blockIdx.x * blockDim.x + threadIdx.x;
    if (t >= NPTS * 198) return;
    int n = t / 198, j = t % 198;
    float acc = 0.f;
#pragma unroll
    for (int c = 0; c < 3; c++) {
        acc += x[n * 3 + c] * wc[c * 198 + j];
        acc += pos[n * 3 + c] * wc[(3 + c) * 198 + j];
    }
    z[(size_t)n * LDZ + j] = acc;
}

// ---------------- fused weight transpose + split (MFMA weights, one launch) ----------
struct WArgs {
    const float* src[NSEG];
    ushort_t* dst[NSEG];
    int K[NSEG], N[NSEG], Kp[NSEG], t0[NSEG];
};
__global__ void k_wsplit_all(WArgs a) {
    int bt = blockIdx.x;
    int si = 0;
#pragma unroll
    for (int i = 1; i < NSEG; i++) if (bt >= a.t0[i]) si = i;
    int t = bt - a.t0[si];
    int K_ = a.K[si], N_ = a.N[si], Kp = a.Kp[si];
    const float* src = a.src[si];
    ushort_t* dh = a.dst[si];
    ushort_t* dl = dh + (size_t)Kp * N_;
    int tX = (N_ + 31) >> 5;
    int k0 = (t / tX) * 32, n0 = (t % tX) * 32;
    __shared__ float tt[32][33];
    int c = threadIdx.x & 31, r8 = threadIdx.x >> 5;
#pragma unroll
    for (int i = 0; i < 4; i++) {
        int r = r8 + i * 8;
        int k = k0 + r, n = n0 + c;
        tt[r][c] = (k < K_ && n < N_) ? src[(size_t)k * N_ + n] : 0.f;
    }
    __syncthreads();
#pragma unroll
    for (int i = 0; i < 4; i++) {
        int r = r8 + i * 8;
        int n = n0 + r, k = k0 + c;
        if (n < N_) {
            float v = tt[c][r];
            ushort_t h, l; split2(v, h, l);
            dh[(size_t)n * Kp + k] = h;
            dl[(size_t)n * Kp + k] = l;
        }
    }
}

// -------- pure-bf16 MFMA GEMM, software-pipelined; fusable epilogues:
//   lsm: log_softmax over Ndim cols;  gmax: column-max (no C write) --------
template<int MT, int NT>
__global__ __launch_bounds__(256)
void k_mgemm1(const ushort_t* __restrict__ A, int lda,
              const ushort_t* __restrict__ W, int ldw,
              float* __restrict__ Cf, int ldc,
              ushort_t* __restrict__ Ch, int ldh,
              int Ndim, int K,
              const float* __restrict__ bias1, const float* __restrict__ bias2,
              int relu, int lsm, uint_t* __restrict__ gmax) {
    constexpr int MTW = MT / 64;
    constexpr int NTT = NT / 16;
    __shared__ ushort_t As[2][MT * 40];
    __shared__ ushort_t Bs[2][NT * 40];
    __shared__ uint_t smax[NT];
    int tid = threadIdx.x;
    int w = tid >> 6, lane = tid & 63;
    int quad = lane >> 4, l16 = lane & 15;
    int m0 = blockIdx.x * MT, n0 = blockIdx.y * NT;
    uint4_t pa[MT / 64], pb[NT / 64];
    auto prefetch = [&](int k0) {
#pragma unroll
        for (int rep = 0; rep < MT / 64; rep++) {
            int idx = tid + rep * 256;
            int row = idx >> 2, q = idx & 3;
            pa[rep] = *(const uint4_t*)(A + (size_t)(m0 + row) * lda + k0 + q * 8);
        }
#pragma unroll
        for (int rep = 0; rep < NT / 64; rep++) {
            int idx = tid + rep * 256;
            int row = idx >> 2, q = idx & 3;
            uint4_t v = {0, 0, 0, 0};
            if (n0 + row < Ndim) v = *(const uint4_t*)(W + (size_t)(n0 + row) * ldw + k0 + q * 8);
            pb[rep] = v;
        }
    };
    auto stage = [&](int buf) {
#pragma unroll
        for (int rep = 0; rep < MT / 64; rep++) {
            int idx = tid + rep * 256;
            int row = idx >> 2, q = idx & 3;
            *(uint4_t*)&As[buf][row * 40 + q * 8] = pa[rep];
        }
#pragma unroll
        for (int rep = 0; rep < NT / 64; rep++) {
            int idx = tid + rep * 256;
            int row = idx >> 2, q = idx & 3;
            *(uint4_t*)&Bs[buf][row * 40 + q * 8] = pb[rep];
        }
    };
    if (gmax) {
        for (int idx = tid; idx < NT; idx += 256) smax[idx] = 0u;
    }
    floatx4 acc[MTW][NTT] = {};
    prefetch(0);
    stage(0);
    __syncthreads();
    int cur = 0;
    for (int k0 = 0; k0 < K; k0 += 32) {
        bool more = (k0 + 32 < K);
        if (more) prefetch(k0 + 32);
        short8 ah[MTW];
#pragma unroll
        for (int mt = 0; mt < MTW; mt++) {
            int r = w * (MT / 4) + mt * 16 + l16;
            ah[mt] = *(short8*)&As[cur][r * 40 + quad * 8];
        }
#pragma unroll
        for (int nt = 0; nt < NTT; nt++) {
            int r = nt * 16 + l16;
            short8 bh = *(short8*)&Bs[cur][r * 40 + quad * 8];
#pragma unroll
            for (int mt = 0; mt < MTW; mt++)
                acc[mt][nt] = __builtin_amdgcn_mfma_f32_16x16x32_bf16(ah[mt], bh, acc[mt][nt], 0, 0, 0);
        }
        if (more) stage(cur ^ 1);
        __syncthreads();
        cur ^= 1;
    }
    if (lsm) {
#pragma unroll
        for (int mt = 0; mt < MTW; mt++) {
#pragma unroll
            for (int r = 0; r < 4; r++) {
                float vv[NTT];
                float mrow = -3e38f;
#pragma unroll
                for (int nt = 0; nt < NTT; nt++) {
                    int n = n0 + nt * 16 + l16;
                    float val = (n < Ndim) ? acc[mt][nt][r] + bias1[n] : -3e38f;
                    vv[nt] = val;
                    mrow = fmaxf(mrow, val);
                }
#pragma unroll
                for (int off = 8; off >= 1; off >>= 1)
                    mrow = fmaxf(mrow, __shfl_xor(mrow, off, 64));
                float s = 0.f;
#pragma unroll
                for (int nt = 0; nt < NTT; nt++)
                    if (vv[nt] > -1e38f) s += expf(vv[nt] - mrow);
#pragma unroll
                for (int off = 8; off >= 1; off >>= 1)
                    s += __shfl_xor(s, off, 64);
                float lse = mrow + logf(s);
                int m = m0 + w * (MT / 4) + mt * 16 + quad * 4 + r;
#pragma unroll
                for (int nt = 0; nt < NTT; nt++) {
                    int n = n0 + nt * 16 + l16;
                    if (n < Ndim) Cf[(size_t)m * ldc + n] = vv[nt] - lse;
                }
            }
        }
        return;
    }
    if (gmax) {
#pragma unroll
        for (int mt = 0; mt < MTW; mt++) {
#pragma unroll
            for (int nt = 0; nt < NTT; nt++) {
#pragma unroll
                for (int r = 0; r < 4; r++) {
                    float v = acc[mt][nt][r] + bias1[nt * 16 + l16 + n0];
                    atomicMax(&smax[nt * 16 + l16], fenc(v));
                }
            }
        }
        __syncthreads();
        for (int idx = tid; idx < NT; idx += 256)
            atomicMax(&gmax[n0 + idx], smax[idx]);
        return;
    }
#pragma unroll
    for (int mt = 0; mt < MTW; mt++) {
#pragma unroll
        for (int nt = 0; nt < NTT; nt++) {
#pragma unroll
            for (int r = 0; r < 4; r++) {
                int m = m0 + w * (MT / 4) + mt * 16 + quad * 4 + r;
                int n = n0 + nt * 16 + l16;
                if (n < Ndim) {
                    float v = acc[mt][nt][r];
                    if (bias1) v += bias1[n];
                    if (bias2) v += bias2[n];
                    if (relu && v < 0.f) v = 0.f;
                    if (Cf) Cf[(size_t)m * ldc + n] = v;
                    if (Ch) Ch[(size_t)m * ldh + n] = f2bs(v);
                }
            }
        }
    }
}

// ---------------- split-bf16 (3-term) MFMA GEMM ----------------
__global__ __launch_bounds__(256)
void k_mgemm3(const ushort_t* __restrict__ Ah, const ushort_t* __restrict__ Al, int lda,
              const ushort_t* __restrict__ Wh, const ushort_t* __restrict__ Wl, int ldw,
              float* __restrict__ Cf, int ldc,
              int Ndim, int K) {
    constexpr int NTT = 4;
    __shared__ ushort_t AsH[64 * 40], BsH[64 * 40], AsL[64 * 40], BsL[64 * 40];
    int tid = threadIdx.x;
    int w = tid >> 6, lane = tid & 63;
    int quad = lane >> 4, l16 = lane & 15;
    int m0 = blockIdx.y * 64, n0 = blockIdx.x * 64;
    floatx4 acc[NTT] = {};
    for (int k0 = 0; k0 < K; k0 += 32) {
        {
            int row = tid >> 2, q = tid & 3;
            size_t go = (size_t)(m0 + row) * lda + k0 + q * 8;
            *(uint4_t*)&AsH[row * 40 + q * 8] = *(const uint4_t*)(Ah + go);
            *(uint4_t*)&AsL[row * 40 + q * 8] = *(const uint4_t*)(Al + go);
            uint4_t vh = {0, 0, 0, 0}, vl = {0, 0, 0, 0};
            size_t gw = (size_t)(n0 + row) * ldw + k0 + q * 8;
            if (n0 + row < Ndim) { vh = *(const uint4_t*)(Wh + gw); vl = *(const uint4_t*)(Wl + gw); }
            *(uint4_t*)&BsH[row * 40 + q * 8] = vh;
            *(uint4_t*)&BsL[row * 40 + q * 8] = vl;
        }
        __syncthreads();
        short8 ah, al;
        {
            int r = w * 16 + l16;
            ah = *(short8*)&AsH[r * 40 + quad * 8];
            al = *(short8*)&AsL[r * 40 + quad * 8];
        }
#pragma unroll
        for (int nt = 0; nt < NTT; nt++) {
            int r = nt * 16 + l16;
            short8 bh = *(short8*)&BsH[r * 40 + quad * 8];
            short8 bl = *(short8*)&BsL[r * 40 + quad * 8];
            acc[nt] = __builtin_amdgcn_mfma_f32_16x16x32_bf16(ah, bh, acc[nt], 0, 0, 0);
            acc[nt] = __builtin_amdgcn_mfma_f32_16x16x32_bf16(ah, bl, acc[nt], 0, 0, 0);
            acc[nt] = __builtin_amdgcn_mfma_f32_16x16x32_bf16(al, bh, acc[nt], 0, 0, 0);
        }
        __syncthreads();
    }
#pragma unroll
    for (int nt = 0; nt < NTT; nt++) {
#pragma unroll
        for (int r = 0; r < 4; r++) {
            int m = m0 + w * 16 + quad * 4 + r;
            int n = n0 + nt * 16 + l16;
            if (n < Ndim) Cf[(size_t)m * ldc + n] = acc[nt][r];
        }
    }
}

// ---------------- split-bf16 MFMA pairwise distances -> packed sort keys -----------
// keys stored through cache (L3-resident for the immediately-following k_topk read).
__global__ __launch_bounds__(256)
void k_mdist(const ushort_t* __restrict__ Lh, const ushort_t* __restrict__ Ll,
             int co, int C, uint_t* __restrict__ keys) {
    __shared__ ushort_t AsH[128 * 40], AsL[128 * 40], BsH[64 * 40], BsL[64 * 40];
    __shared__ float sqa[128], sqb[64];
    int tid = threadIdx.x;
    int w = tid >> 6, lane = tid & 63;
    int quad = lane >> 4, l16 = lane & 15;
    int b = blockIdx.z, cb = b * PP;
    int i0 = blockIdx.y * 128, j0 = blockIdx.x * 64;
    floatx4 acc[2][4] = {};
    float sacc = 0.f;
    for (int k0 = 0; k0 < C; k0 += 32) {
#pragma unroll
        for (int rep = 0; rep < 8; rep++) {
            int d = tid + rep * 256;
            int row = d >> 4, c2 = d & 15;
            size_t gi = ((size_t)(cb + i0 + row) * LDH + co + k0 + c2 * 2) >> 1;
            *(uint_t*)&AsH[row * 40 + c2 * 2] = ((const uint_t*)Lh)[gi];
            *(uint_t*)&AsL[row * 40 + c2 * 2] = ((const uint_t*)Ll)[gi];
        }
#pragma unroll
        for (int rep = 0; rep < 4; rep++) {
            int d = tid + rep * 256;
            int row = d >> 4, c2 = d & 15;
            size_t gi = ((size_t)(cb + j0 + row) * LDH + co + k0 + c2 * 2) >> 1;
            *(uint_t*)&BsH[row * 40 + c2 * 2] = ((const uint_t*)Lh)[gi];
            *(uint_t*)&BsL[row * 40 + c2 * 2] = ((const uint_t*)Ll)[gi];
        }
        __syncthreads();
        if (tid < 128) {
#pragma unroll
            for (int kk = 0; kk < 16; kk++) {
                uint_t ph = *(uint_t*)&AsH[tid * 40 + kk * 2];
                uint_t pl = *(uint_t*)&AsL[tid * 40 + kk * 2];
                float v0 = bs2f((ushort_t)(ph & 0xFFFFu)) + bs2f((ushort_t)(pl & 0xFFFFu));
                sacc += v0 * v0;
                float v1 = bs2f((ushort_t)(ph >> 16)) + bs2f((ushort_t)(pl >> 16));
                sacc += v1 * v1;
            }
        } else if (tid < 192) {
            int row = tid - 128;
#pragma unroll
            for (int kk = 0; kk < 16; kk++) {
                uint_t ph = *(uint_t*)&BsH[row * 40 + kk * 2];
                uint_t pl = *(uint_t*)&BsL[row * 40 + kk * 2];
                float v0 = bs2f((ushort_t)(ph & 0xFFFFu)) + bs2f((ushort_t)(pl & 0xFFFFu));
                sacc += v0 * v0;
                float v1 = bs2f((ushort_t)(ph >> 16)) + bs2f((ushort_t)(pl >> 16));
                sacc += v1 * v1;
            }
        }
        short8 ah[2], al[2];
#pragma unroll
        for (int mt = 0; mt < 2; mt++) {
            int r = w * 32 + mt * 16 + l16;
            ah[mt] = *(short8*)&AsH[r * 40 + quad * 8];
            al[mt] = *(short8*)&AsL[r * 40 + quad * 8];
        }
#pragma unroll
        for (int nt = 0; nt < 4; nt++) {
            int r = nt * 16 + l16;
            short8 bh = *(short8*)&BsH[r * 40 + quad * 8];
            short8 bl = *(short8*)&BsL[r * 40 + quad * 8];
#pragma unroll
            for (int mt = 0; mt < 2; mt++) {
                acc[mt][nt] = __builtin_amdgcn_mfma_f32_16x16x32_bf16(ah[mt], bh, acc[mt][nt], 0, 0, 0);
                acc[mt][nt] = __builtin_amdgcn_mfma_f32_16x16x32_bf16(ah[mt], bl, acc[mt][nt], 0, 0, 0);
                acc[mt][nt] = __builtin_amdgcn_mfma_f32_16x16x32_bf16(al[mt], bh, acc[mt][nt], 0, 0, 0);
            }
        }
        __syncthreads();
    }
    if (tid < 128) sqa[tid] = sacc;
    else if (tid < 192) sqb[tid - 128] = sacc;
    __syncthreads();
#pragma unroll
    for (int mt = 0; mt < 2; mt++) {
#pragma unroll
        for (int nt = 0; nt < 4; nt++) {
#pragma unroll
            for (int r = 0; r < 4; r++) {
                int li = w * 32 + mt * 16 + quad * 4 + r;
                int lj = nt * 16 + l16;
                int il = i0 + li, jl = j0 + lj;
                float dd = sqa[li] + sqb[lj] - 2.f * acc[mt][nt][r];
                dd = (il == jl) ? 3e9f : fmaxf(dd, 0.f);
                uint_t key = (__float_as_uint(dd) & 0xFFFFF800u) | (uint_t)jl;
                keys[(size_t)(cb + il) * PP + jl] = key;
            }
        }
    }
}

// ---------------- top-30 smallest per row via packed u32 keys ----------------
__global__ __launch_bounds__(256)
void k_topk(const uint_t* __restrict__ keys, int* __restrict__ nbr) {
    int r = blockIdx.x * 4 + (threadIdx.x >> 6);
    int lane = threadIdx.x & 63;
    int base = (r / PP) * PP;
    const uint_t* row = keys + (size_t)r * PP;
    uint_t v[32];
#pragma unroll
    for (int j = 0; j < 8; j++)
        *(uint4_t*)&v[j * 4] = *(const uint4_t*)(row + lane * 4 + j * 256);
    uint_t g[8];
#pragma unroll
    for (int j = 0; j < 8; j++)
        g[j] = min(min(v[j * 4], v[j * 4 + 1]), min(v[j * 4 + 2], v[j * 4 + 3]));
    uint_t lv = g[0];
#pragma unroll
    for (int j = 1; j < 8; j++) lv = min(lv, g[j]);
    for (int sel = 0; sel < KNN; sel++) {
        uint_t bk = lv;
#pragma unroll
        for (int off = 32; off > 0; off >>= 1)
            bk = min(bk, (uint_t)__shfl_xor((int)bk, off, 64));
        uint_t bks = __builtin_amdgcn_readfirstlane(bk);
        if (lane == 0) nbr[r * KTOT + sel] = base + (int)(bks & 0x7FFu);
        int grp = (int)((bks & 0x7FFu) >> 8);
#pragma unroll
        for (int jj = 0; jj < 8; jj++)
            if (grp == jj) {
#pragma unroll
                for (int t = 0; t < 4; t++)
                    v[jj * 4 + t] = (v[jj * 4 + t] == bks) ? 0xFFFFFFFFu : v[jj * 4 + t];
                g[jj] = min(min(v[jj * 4], v[jj * 4 + 1]), min(v[jj * 4 + 2], v[jj * 4 + 3]));
            }
        lv = g[0];
#pragma unroll
        for (int j = 1; j < 8; j++) lv = min(lv, g[j]);
    }
    if (lane == 0) nbr[r * KTOT + KNN] = r;
}

// ---------------- GAT edge-softmax + aggregate, fp32 z (stages 1-2) ----------------
// z row: [3F proj | 3 src-scores | 3 dst-scores].  NN nodes/block, 192 threads.
template<int F, int NN>
__global__ __launch_bounds__(192)
void k_gat2(const float* __restrict__ z, int ldz,
            const int* __restrict__ nbr,
            const float* __restrict__ bc,
            ushort_t* __restrict__ dh, ushort_t* __restrict__ dl) {
    constexpr int TPN = 3 * F / 4;   // threads per node in aggregate (48 or 96)
    __shared__ int srcs[NN][KTOT];
    __shared__ float alpha[NN][96];
    __shared__ float part[NN][2][F];
    int tid = threadIdx.x;
    if (tid < NN * KTOT) {
        int u = tid / KTOT, k = tid % KTOT;
        int t = blockIdx.x * NN + u;
        int node = (t & 3) * PP + (t >> 2);
        srcs[u][k] = nbr[node * KTOT + k];
    }
    __syncthreads();
#pragma unroll
    for (int u2 = 0; u2 < NN; u2 += 2) {
        int u = u2 + tid / 96;       // 2 nodes per 192-thread pass; 32-lane aligned groups
        int r = tid % 96, h = r >> 5, k = r & 31;
        int t = blockIdx.x * NN + u;
        int node = (t & 3) * PP + (t >> 2);
        float e = -3e38f;
        if (k < KTOT) {
            float sv = z[(size_t)srcs[u][k] * ldz + 3 * F + h];
            float tv = z[(size_t)node * ldz + 3 * F + 3 + h];
            e = sv + tv;
            if (e < 0.f) e *= 0.2f;
        }
        float m = e;
#pragma unroll
        for (int off = 16; off >= 1; off >>= 1)
            m = fmaxf(m, __shfl_xor(m, off, 32));
        float ex = (k < KTOT) ? expf(e - m) : 0.f;
        float s = ex;
#pragma unroll
        for (int off = 16; off >= 1; off >>= 1)
            s += __shfl_xor(s, off, 32);
        alpha[u][h * 32 + k] = ex / s;
    }
    __syncthreads();
    // aggregate: thread -> (u, h, j-quad); float4 gathers, 2 vector accumulators
    {
        int u = tid / TPN, r = tid % TPN;
        int h = r / (F / 4), jq = r % (F / 4);
        const float* zb = z + h * F + jq * 4;
        floatx4 a0 = {0.f, 0.f, 0.f, 0.f}, a1 = {0.f, 0.f, 0.f, 0.f};
#pragma unroll
        for (int k = 0; k < KTOT; k += 2) {
            float a = alpha[u][h * 32 + k];
            floatx4 p = *(const floatx4*)(zb + (size_t)srcs[u][k] * ldz);
            a0 += p * a;
            if (k + 1 < KTOT) {
                float a2 = alpha[u][h * 32 + k + 1];
                floatx4 p2 = *(const floatx4*)(zb + (size_t)srcs[u][k + 1] * ldz);
                a1 += p2 * a2;
            }
        }
        floatx4 av = a0 + a1;
        if (h > 0)
            *(floatx4*)&part[u][h - 1][jq * 4] = av;
        __syncthreads();
        if (h == 0) {
            int t = blockIdx.x * NN + u;
            int node = (t & 3) * PP + (t >> 2);
            int j0 = jq * 4;
            floatx4 p0 = *(const floatx4*)&part[u][0][j0];
            floatx4 p1 = *(const floatx4*)&part[u][1][j0];
            floatx4 bcv = *(const floatx4*)&bc[j0];
            floatx4 v = av + p0 + p1 + bcv;
            ushort_t hh[4], ll[4];
#pragma unroll
            for (int q = 0; q < 4; q++) split2(v[q], hh[q], ll[q]);
            *(uint_t*)&dh[(size_t)node * LDH + j0] = (uint_t)hh[0] | ((uint_t)hh[1] << 16);
            *(uint_t*)&dh[(size_t)node * LDH + j0 + 2] = (uint_t)hh[2] | ((uint_t)hh[3] << 16);
            if (dl) {
                *(uint_t*)&dl[(size_t)node * LDH + j0] = (uint_t)ll[0] | ((uint_t)ll[1] << 16);
                *(uint_t*)&dl[(size_t)node * LDH + j0 + 2] = (uint_t)ll[2] | ((uint_t)ll[3] << 16);
            }
        }
    }
}

// ---------------- GAT edge-softmax + aggregate, bf16 z (stages 3-4) ----------------
// z stored bf16 -> half the gather bytes.  Thread owns (node, head, j-oct):
// short8 gathers (16B = 8 cols), 8 independent FMA chains.  All 192 threads active.
template<int F, int NN>
__global__ __launch_bounds__(192)
void k_gat2b(const ushort_t* __restrict__ z, int ldz,
             const int* __restrict__ nbr,
             const float* __restrict__ bc,
             ushort_t* __restrict__ dh) {
    constexpr int TPN = 3 * F / 8;   // 24 (F=64, NN=8) or 48 (F=128, NN=4)
    __shared__ int srcs[NN][KTOT];
    __shared__ float alpha[NN][96];
    __shared__ float part[NN][2][F];
    int tid = threadIdx.x;
    for (int idx = tid; idx < NN * KTOT; idx += 192) {
        int u = idx / KTOT, k = idx % KTOT;
        int t = blockIdx.x * NN + u;
        int node = (t & 3) * PP + (t >> 2);
        srcs[u][k] = nbr[node * KTOT + k];
    }
    __syncthreads();
#pragma unroll
    for (int u2 = 0; u2 < NN; u2 += 2) {
        int u = u2 + tid / 96;
        int r = tid % 96, h = r >> 5, k = r & 31;
        int t = blockIdx.x * NN + u;
        int node = (t & 3) * PP + (t >> 2);
        float e = -3e38f;
        if (k < KTOT) {
            float sv = bs2f(z[(size_t)srcs[u][k] * ldz + 3 * F + h]);
            float tv = bs2f(z[(size_t)node * ldz + 3 * F + 3 + h]);
            e = sv + tv;
            if (e < 0.f) e *= 0.2f;
        }
        float m = e;
#pragma unroll
        for (int off = 16; off >= 1; off >>= 1)
            m = fmaxf(m, __shfl_xor(m, off, 32));
        float ex = (k < KTOT) ? expf(e - m) : 0.f;
        float s = ex;
#pragma unroll
        for (int off = 16; off >= 1; off >>= 1)
            s += __shfl_xor(s, off, 32);
        alpha[u][h * 32 + k] = ex / s;
    }
    __syncthreads();
    {
        int u = tid / TPN, r = tid % TPN;
        int h = r / (F / 8), jo = r % (F / 8);
        const ushort_t* zb = z + h * F + jo * 8;
        float a[8] = {};
        for (int k = 0; k < KTOT; k++) {
            float al = alpha[u][h * 32 + k];
            short8 v = *(const short8*)(zb + (size_t)srcs[u][k] * ldz);
#pragma unroll
            for (int q = 0; q < 8; q++)
                a[q] += al * bs2f((ushort_t)v[q]);
        }
        if (h > 0) {
#pragma unroll
            for (int q = 0; q < 8; q++) part[u][h - 1][jo * 8 + q] = a[q];
        }
        __syncthreads();
        if (h == 0) {
            int t = blockIdx.x * NN + u;
            int node = (t & 3) * PP + (t >> 2);
            int j0 = jo * 8;
#pragma unroll
            for (int q2 = 0; q2 < 4; q2++) {
                float v0 = a[q2 * 2] + part[u][0][j0 + q2 * 2] + part[u][1][j0 + q2 * 2] + bc[j0 + q2 * 2];
                float v1 = a[q2 * 2 + 1] + part[u][0][j0 + q2 * 2 + 1] + part[u][1][j0 + q2 * 2 + 1] + bc[j0 + q2 * 2 + 1];
                *(uint_t*)&dh[(size_t)node * LDH + j0 + q2 * 2] =
                    (uint_t)f2bs(v0) | ((uint_t)f2bs(v1) << 16);
            }
        }
    }
}

// ---------------- gproj: decode fused column max + split-K matmul ----------------
__global__ void k_gproj(const uint_t* __restrict__ genc,
                        const float* __restrict__ mw1,
                        const float* __restrict__ mb1,
                        float* __restrict__ gproj) {
    __shared__ float gs[128];
    int kb = blockIdx.x;           // 8 blocks x 128 k
    int t = threadIdx.x;           // 256
    if (t < 128) gs[t] = fdec(genc[kb * 128 + t]);
    __syncthreads();
    float acc = (kb == 0) ? mb1[t] : 0.f;
    for (int k = 0; k < 128; k++)
        acc += gs[k] * mw1[(size_t)(326 + kb * 128 + k) * 256 + t];
    atomicAdd(&gproj[t], acc);
}

// ---------------- host side ----------------
struct WT { ushort_t *h, *l; int kp; };

extern "C" void kernel_launch(void* const* d_in, const int* in_sizes, int n_in,
                              void* d_out, int out_size, void* d_ws, size_t ws_size,
                              hipStream_t stream) {
    (void)in_sizes; (void)n_in; (void)out_size; (void)ws_size;
    const float* x    = (const float*)d_in[0];
    const float* pos  = (const float*)d_in[1];
    const float* w1   = (const float*)d_in[3];
    const float* as1  = (const float*)d_in[4];
    const float* ad1  = (const float*)d_in[5];
    const float* b1   = (const float*)d_in[6];
    const float* ml1w = (const float*)d_in[7];
    const float* ml1b = (const float*)d_in[8];
    const float* w2   = (const float*)d_in[9];
    const float* as2  = (const float*)d_in[10];
    const float* ad2  = (const float*)d_in[11];
    const float* b2   = (const float*)d_in[12];
    const float* ml2w = (const float*)d_in[13];
    const float* ml2b = (const float*)d_in[14];
    const float* w3   = (const float*)d_in[15];
    const float* as3  = (const float*)d_in[16];
    const float* ad3  = (const float*)d_in[17];
    const float* b3   = (const float*)d_in[18];
    const float* ml3w = (const float*)d_in[19];
    const float* ml3b = (const float*)d_in[20];
    const float* w4   = (const float*)d_in[21];
    const float* as4  = (const float*)d_in[22];
    const float* ad4  = (const float*)d_in[23];
    const float* b4   = (const float*)d_in[24];
    const float* ml4w = (const float*)d_in[25];
    const float* ml4b = (const float*)d_in[26];
    const float* few1 = (const float*)d_in[27];
    const float* feb1 = (const float*)d_in[28];
    const float* few2 = (const float*)d_in[29];
    const float* feb2 = (const float*)d_in[30];
    const float* mw1  = (const float*)d_in[31];
    const float* mb1  = (const float*)d_in[32];
    const float* mw2  = (const float*)d_in[33];
    const float* mb2  = (const float*)d_in[34];
    const float* mw3  = (const float*)d_in[35];
    const float* mb3  = (const float*)d_in[36];
    const float* mw4  = (const float*)d_in[37];
    const float* mb4  = (const float*)d_in[38];

    float* Wb = (float*)d_ws;
    size_t off = 0;
    auto alloc = [&](size_t n) { float* p = Wb + off; off += (n + 63) & ~(size_t)63; return p; };

    float*    dist = alloc((size_t)NPTS * PP);                  // 67 MB aliased region
    ushort_t* l4h  = (ushort_t*)alloc((size_t)NPTS * LDH / 2);
    ushort_t* l4l  = (ushort_t*)alloc((size_t)NPTS * LDH / 2);
    // genc|gproj|bcp contiguous -> single memset
    uint_t* genc = (uint_t*)alloc(1024);                        // encoded col maxima
    float* gproj = alloc(256);
    float* bcp = alloc(320);                                    // bc1|bc2|bc3|bc4
    float* bc1 = bcp, *bc2 = bcp + 64, *bc3 = bcp + 128, *bc4 = bcp + 192;
    int*   nbr   = (int*)alloc((size_t)NPTS * KTOT);
    ushort_t* wtpool = (ushort_t*)alloc(1742336);
    float* wc1 = alloc(6 * 198);
    float* wc2 = alloc(70 * 198);
    float* wc3 = alloc(134 * 198);
    float* wc4 = alloc(198 * 390);

    // aliases inside dist region (disjoint lifetimes):
    //   dkey lives between k_mdist and k_topk; z/zb written AFTER topk consumed keys,
    //   dead before next k_mdist; hah/bAh/bBh/bCh live in the fe/head phase only.
    char* d0 = (char*)dist;
    uint_t*   dkey = (uint_t*)dist;
    float*    z    = dist;
    ushort_t* zb   = (ushort_t*)dist;                           // bf16 z (stages 3-4)
    ushort_t* hah  = (ushort_t*)d0;                             // fe1 out hi (16.8MB)
    ushort_t* bBh  = (ushort_t*)(d0 + (size_t)NPTS * 1024 * 2); // mw2 out hi
    ushort_t* bAh = (ushort_t*)d0;                              // mw1 out hi (hah dead)
    ushort_t* bCh = (ushort_t*)d0;                              // mw3 out hi (bAh dead)

    // ---- zero link4 planes + accumulators ----
    hipMemsetAsync(l4h, 0, (size_t)NPTS * LDH * 4, stream);     // covers hi+lo (contiguous)
    hipMemsetAsync(genc, 0, (1024 + 256 + 320) * 4, stream);    // genc|gproj|bcp

    // ---- combined GAT weights (ml-proj + scores folded into producing GEMM) ----
    {
        C64 ca;
        const float* ws_[3] = {w1, w2, w3};
        const float* mlws[3] = {ml1w, ml2w, ml3w};
        const float* ass[3] = {as1, as2, as3};
        const float* ads[3] = {ad1, ad2, ad3};
        const float* bs_[3] = {b1, b2, b3};
        const float* mlbs[3] = {ml1b, ml2b, ml3b};
        float* wcs[3] = {wc1, wc2, wc3};
        float* bcs[3] = {bc1, bc2, bc3};
        int Ks[3] = {6, 70, 134};
        int t = 0;
        for (int i = 0; i < 3; i++) {
            ca.w[i] = ws_[i]; ca.mlw[i] = mlws[i]; ca.as_[i] = ass[i]; ca.ad[i] = ads[i];
            ca.b[i] = bs_[i]; ca.mlb[i] = mlbs[i]; ca.wc[i] = wcs[i]; ca.bc[i] = bcs[i];
            ca.K[i] = Ks[i]; ca.t0[i] = t;
            t += ((Ks[i] + 7) / 8) * 3;
        }
        k_combine64<<<t, 128, 0, stream>>>(ca);
        k_combine128<<<25 * 3, 128, 0, stream>>>(w4, ml4w, as4, ad4, b4, ml4b, wc4, bc4, 198);
    }

    // ---- fused weight transpose+split (MFMA weights; combined ones from wc*) ----
    WArgs wa;
    WT wt[NSEG];
    {
        const float* srcs[NSEG] = {wc2, wc3, wc4, few1, few2, mw1, mw2, mw3, mw4};
        int Ks[NSEG] = {70, 134, 198, 326, 1024, 326, 256, 256, 128};
        int Ns[NSEG] = {198, 198, 390, 1024, 1024, 256, 256, 128, 50};
        size_t wo = 0; int tiles = 0;
        for (int i = 0; i < NSEG; i++) {
            int kp = (Ks[i] + 31) & ~31;
            wa.src[i] = srcs[i];
            wa.dst[i] = wtpool + wo;
            wa.K[i] = Ks[i]; wa.N[i] = Ns[i]; wa.Kp[i] = kp;
            wa.t0[i] = tiles;
            wt[i] = { wtpool + wo, wtpool + wo + (size_t)kp * Ns[i], kp };
            wo += (size_t)2 * kp * Ns[i];
            tiles += (kp / 32) * ((Ns[i] + 31) / 32);
        }
        k_wsplit_all<<<tiles, 256, 0, stream>>>(wa);
    }
    WT tw2 = wt[0], tw3 = wt[1], tw4 = wt[2], tfe1 = wt[3], tfe2 = wt[4],
       tmw1 = wt[5], tmw2 = wt[6], tmw3 = wt[7], tmw4 = wt[8];

    auto mg3 = [&](const ushort_t* Ah, const ushort_t* Al, int lda, WT t,
                   float* Cf, int ldc, int Nd, int K) {
        dim3 g((Nd + 63) / 64, NPTS / 64);
        k_mgemm3<<<g, 256, 0, stream>>>(Ah, Al, lda, t.h, t.l, t.kp, Cf, ldc, Nd, K);
    };
    auto mg1 = [&](int MT, int NT, const ushort_t* Ah, int lda, WT t,
                   float* Cf, int ldc, ushort_t* Ch, int ldhh,
                   int Nd, int K, const float* bb1, const float* bb2,
                   int relu, int lsm, uint_t* gmax) {
        dim3 g(NPTS / MT, (Nd + NT - 1) / NT);
        if (MT == 128 && NT == 128)
            k_mgemm1<128, 128><<<g, 256, 0, stream>>>(Ah, lda, t.h, t.kp, Cf, ldc, Ch, ldhh, Nd, K,
                bb1, bb2, relu, lsm, gmax);
        else if (MT == 128)
            k_mgemm1<128, 64><<<g, 256, 0, stream>>>(Ah, lda, t.h, t.kp, Cf, ldc, Ch, ldhh, Nd, K,
                bb1, bb2, relu, lsm, gmax);
        else
            k_mgemm1<64, 64><<<g, 256, 0, stream>>>(Ah, lda, t.h, t.kp, Cf, ldc, Ch, ldhh, Nd, K,
                bb1, bb2, relu, lsm, gmax);
    };

    dim3 dgrid(PP / 64, PP / 128, 4);
    k_build_x0<<<(NPTS * 6 + 255) / 256, 256, 0, stream>>>(x, pos, l4h, l4l);

    // ---- stage 1: knn on x0 (C=6; cols 6..31 still zero); tw1 AFTER topk; gat -> x1 ----
    k_mdist<<<dgrid, 256, 0, stream>>>(l4h, l4l, 0, 6, dkey);
    k_topk<<<NPTS / 4, 256, 0, stream>>>(dkey, nbr);
    k_tw1<<<(NPTS * 198 + 255) / 256, 256, 0, stream>>>(x, pos, wc1, z);
    k_gat2<64, 4><<<NPTS / 4, 192, 0, stream>>>(z, LDZ, nbr, bc1, l4h + 6, l4l + 6);

    // ---- stage 2: knn on x1 (C=64); split-bf16 GEMM -> z2 (proj+scores); gat -> x2 ----
    k_mdist<<<dgrid, 256, 0, stream>>>(l4h, l4l, 6, 64, dkey);
    k_topk<<<NPTS / 4, 256, 0, stream>>>(dkey, nbr);
    mg3(l4h, l4l, LDH, tw2, z, LDZ, 198, 70);
    k_gat2<64, 4><<<NPTS / 4, 192, 0, stream>>>(z, LDZ, nbr, bc2, l4h + 70, l4l + 70);

    // ---- stage 3: knn on x2 (C=64); hi-only GEMM -> zb3 (bf16); gat -> x3 (hi only) ----
    k_mdist<<<dgrid, 256, 0, stream>>>(l4h, l4l, 70, 64, dkey);
    k_topk<<<NPTS / 4, 256, 0, stream>>>(dkey, nbr);
    mg1(128, 64, l4h, LDH, tw3, nullptr, 0, zb, LDZB3, 198, 134, nullptr, nullptr, 0, 0, nullptr);
    k_gat2b<64, 8><<<NPTS / 8, 192, 0, stream>>>(zb, LDZB3, nbr, bc3, l4h + 134);

    // ---- stage 4 (reuses stage-3 nbr): GEMM -> zb4 (bf16); gat(F=128) -> x4 (hi only) ----
    mg1(128, 64, l4h, LDH, tw4, nullptr, 0, zb, LDZB4, 390, 198, nullptr, nullptr, 0, 0, nullptr);
    k_gat2b<128, 4><<<NPTS / 4, 192, 0, stream>>>(zb, LDZB4, nbr, bc4, l4h + 198);

    // ---- fe_mlp: fe1 -> bf16 acts; fe2 -> fused global column max (no C write) ----
    mg1(128, 128, l4h, LDH, tfe1, nullptr, 0, hah, 1024, 1024, 326, feb1, nullptr, 1, 0, nullptr);
    mg1(128, 128, hah, 1024, tfe2, nullptr, 0, nullptr, 0, 1024, 1024, feb2, nullptr, 0, 0, genc);
    k_gproj<<<8, 256, 0, stream>>>(genc, mw1, mb1, gproj);

    // ---- head (bf16 tier; mw4 fuses log_softmax and writes d_out) ----
    mg1(128, 64, l4h, LDH, tmw1, nullptr, 0, bAh, 256, 256, 326, nullptr, gproj, 1, 0, nullptr);
    mg1(128, 64, bAh, 256, tmw2, nullptr, 0, bBh, 256, 256, 256, mb2, nullptr, 1, 0, nullptr);
    mg1(64, 64, bBh, 256, tmw3, nullptr, 0, bCh, 128, 128, 256, mb3, nullptr, 1, 0, nullptr);
    mg1(64, 64, bCh, 128, tmw4, (float*)d_out, 50, nullptr, 0, 50, 128, mb4, nullptr, 0, 1, nullptr);
}

// Round 11
// 503.929 us; speedup vs baseline: 1.0916x; 1.0303x over previous
//
#include <hip/hip_runtime.h>
#include <hip/hip_bf16.h>
#include <hip/amd_detail/amd_hip_vector_types.h>

#define NPTS 8192
#define PP 2048
#define KNN 30
#define KTOT 31
#define HEADS 3
#define LDH 352   // padded ld for link4 hi/lo (bf16): >= Kpad32(326), mult of 8
#define NSEG 9
#define LDZ 200   // z ld stages 1-2 (fp32): 198 cols = 192 proj + 3 s + 3 t
#define LDZB3 200 // z ld stage 3 (bf16 ushorts)
#define LDZB4 392 // z ld stage 4 (bf16 ushorts): 390 cols = 384 proj + 3 s + 3 t

typedef __attribute__((ext_vector_type(8))) short short8;
typedef __attribute__((ext_vector_type(4))) float floatx4;
typedef __attribute__((ext_vector_type(4))) unsigned int uint4_t;
typedef unsigned short ushort_t;
typedef unsigned int uint_t;

__device__ inline ushort_t f2bs(float v) {
    __hip_bfloat16 b = __float2bfloat16(v);
    return *reinterpret_cast<ushort_t*>(&b);
}
__device__ inline float bs2f(ushort_t u) {
    __hip_bfloat16 b = *reinterpret_cast<__hip_bfloat16*>(&u);
    return __bfloat162float(b);
}
__device__ inline void split2(float v, ushort_t& h, ushort_t& l) {
    h = f2bs(v);
    l = f2bs(v - bs2f(h));
}
// order-preserving fp32 <-> uint mapping for atomic max
__device__ inline uint_t fenc(float f) {
    uint_t b = __float_as_uint(f);
    return (b & 0x80000000u) ? ~b : (b | 0x80000000u);
}
__device__ inline float fdec(uint_t e) {
    return __uint_as_float((e & 0x80000000u) ? (e & 0x7FFFFFFFu) : ~e);
}

// ---------------- build x0 (hi/lo) into link4 cols 0..5 ----------------
__global__ void k_build_x0(const float* __restrict__ x, const float* __restrict__ pos,
                           ushort_t* __restrict__ lh, ushort_t* __restrict__ ll) {
    int i = blockIdx.x * blockDim.x + threadIdx.x;
    if (i >= NPTS * 6) return;
    int n = i / 6, c = i % 6;
    float v = (c < 3) ? x[n * 3 + c] : pos[n * 3 + (c - 3)];
    ushort_t h, l; split2(v, h, l);
    lh[(size_t)n * LDH + c] = h;
    ll[(size_t)n * LDH + c] = l;
}

// ---------------- combined GAT weights: Wc = [W*blkdiag(mlW) | W*a_src | W*a_dst],
//                  bc = b*blkdiag(mlW) + mlb  (per stage, exact fp32) ----------------
template<int F_>
__device__ inline void combine_body(const float* __restrict__ w, const float* __restrict__ mlw,
                                    const float* __restrict__ as_, const float* __restrict__ ad,
                                    const float* __restrict__ b, const float* __restrict__ mlb,
                                    float* __restrict__ wc, float* __restrict__ bc,
                                    int K_, int lb) {
    constexpr int NC = 3 * F_ + 6;
    constexpr int JG = 128 / F_;   // row-groups (2 for F=64, 1 for F=128)
    constexpr int RG = 8 / JG;     // rows per thread
    int h = lb % 3, kb = lb / 3;
    int k0 = kb * 8, KS = min(8, K_ - k0);
    int tid = threadIdx.x;
    int j = tid % F_, rg = tid / F_;
    __shared__ float ws[8][F_];
    __shared__ float ms[32][F_];
    __shared__ float bav[3][F_];
    for (int idx = tid; idx < 8 * F_; idx += 128) {
        int r = idx / F_, f = idx % F_;
        ws[r][f] = (r < KS) ? w[(size_t)(k0 + r) * (3 * F_) + h * F_ + f] : 0.f;
    }
    for (int f = tid; f < F_; f += 128) {
        bav[0][f] = b[h * F_ + f];
        bav[1][f] = as_[h * F_ + f];
        bav[2][f] = ad[h * F_ + f];
    }
    __syncthreads();
    const float* mh = mlw + (size_t)h * F_ * F_;
    float acc[RG] = {};
    float bacc = 0.f;
    for (int f0 = 0; f0 < F_; f0 += 32) {
        for (int idx = tid; idx < 32 * F_; idx += 128) {
            int u = idx / F_, jj = idx % F_;
            ms[u][jj] = mh[(size_t)(f0 + u) * F_ + jj];
        }
        __syncthreads();
#pragma unroll
        for (int u = 0; u < 32; u++) {
            float m = ms[u][j];
#pragma unroll
            for (int r = 0; r < RG; r++)
                acc[r] += ws[rg * RG + r][f0 + u] * m;
            if (rg == 0) bacc += bav[0][f0 + u] * m;
        }
        __syncthreads();
    }
#pragma unroll
    for (int r = 0; r < RG; r++) {
        int k = k0 + rg * RG + r;
        if (k < K_) wc[(size_t)k * NC + h * F_ + j] = acc[r];
    }
    if (kb == 0 && rg == 0)
        atomicAdd(&bc[j], bacc + (h == 0 ? mlb[j] : 0.f));
    // score columns: threads (r, src/dst) from staged w-slab (LDS, unrolled)
    if (tid < 16) {
        int r = tid >> 1, sc = tid & 1;
        if (r < KS) {
            float s = 0.f;
#pragma unroll
            for (int f = 0; f < F_; f++) s += ws[r][f] * bav[1 + sc][f];
            wc[(size_t)(k0 + r) * NC + 3 * F_ + sc * 3 + h] = s;
        }
    }
}

struct CAll {
    const float *w[4], *mlw[4], *as_[4], *ad[4], *b[4], *mlb[4];
    float *wc[4], *bc[4];
    int K[4], t0[4], t64;
};
__global__ __launch_bounds__(128)
void k_combine_all(CAll a) {
    int bt = blockIdx.x;
    if (bt < a.t64) {
        int si = 0;
#pragma unroll
        for (int i = 1; i < 3; i++) if (bt >= a.t0[i]) si = i;
        combine_body<64>(a.w[si], a.mlw[si], a.as_[si], a.ad[si], a.b[si], a.mlb[si],
                         a.wc[si], a.bc[si], a.K[si], bt - a.t0[si]);
    } else {
        combine_body<128>(a.w[3], a.mlw[3], a.as_[3], a.ad[3], a.b[3], a.mlb[3],
                          a.wc[3], a.bc[3], a.K[3], bt - a.t64);
    }
}

// ---------------- tw1: z = [x|pos] @ Wc1, exact fp32 (K=6, N=198) ----------------
// NOTE: z aliases the dist/key region -> must run AFTER k_topk consumed the keys.
__global__ void k_tw1(const float* __restrict__ x, const float* __restrict__ pos,
                      const float* __restrict__ wc, float* __restrict__ z) {
    int t = blockIdx.x * blockDim.x + threadIdx.x;
    if (t >= NPTS * 198) return;
    int n = t / 198, j = t % 198;
    float acc = 0.f;
#pragma unroll
    for (int c = 0; c < 3; c++) {
        acc += x[n * 3 + c] * wc[c * 198 + j];
        acc += pos[n * 3 + c] * wc[(3 + c) * 198 + j];
    }
    z[(size_t)n * LDZ + j] = acc;
}

// ---------------- fused weight transpose + split (MFMA weights, one launch) ----------
struct WArgs {
    const float* src[NSEG];
    ushort_t* dst[NSEG];
    int K[NSEG], N[NSEG], Kp[NSEG], t0[NSEG];
};
__global__ void k_wsplit_all(WArgs a) {
    int bt = blockIdx.x;
    int si = 0;
#pragma unroll
    for (int i = 1; i < NSEG; i++) if (bt >= a.t0[i]) si = i;
    int t = bt - a.t0[si];
    int K_ = a.K[si], N_ = a.N[si], Kp = a.Kp[si];
    const float* src = a.src[si];
    ushort_t* dh = a.dst[si];
    ushort_t* dl = dh + (size_t)Kp * N_;
    int tX = (N_ + 31) >> 5;
    int k0 = (t / tX) * 32, n0 = (t % tX) * 32;
    __shared__ float tt[32][33];
    int c = threadIdx.x & 31, r8 = threadIdx.x >> 5;
#pragma unroll
    for (int i = 0; i < 4; i++) {
        int r = r8 + i * 8;
        int k = k0 + r, n = n0 + c;
        tt[r][c] = (k < K_ && n < N_) ? src[(size_t)k * N_ + n] : 0.f;
    }
    __syncthreads();
#pragma unroll
    for (int i = 0; i < 4; i++) {
        int r = r8 + i * 8;
        int n = n0 + r, k = k0 + c;
        if (n < N_) {
            float v = tt[c][r];
            ushort_t h, l; split2(v, h, l);
            dh[(size_t)n * Kp + k] = h;
            dl[(size_t)n * Kp + k] = l;
        }
    }
}

// -------- pure-bf16 MFMA GEMM, software-pipelined; fusable epilogues:
//   lsm: log_softmax over Ndim cols;  gmax: column-max (no C write) --------
template<int MT, int NT>
__global__ __launch_bounds__(256)
void k_mgemm1(const ushort_t* __restrict__ A, int lda,
              const ushort_t* __restrict__ W, int ldw,
              float* __restrict__ Cf, int ldc,
              ushort_t* __restrict__ Ch, int ldh,
              int Ndim, int K,
              const float* __restrict__ bias1, const float* __restrict__ bias2,
              int relu, int lsm, uint_t* __restrict__ gmax) {
    constexpr int MTW = MT / 64;
    constexpr int NTT = NT / 16;
    __shared__ ushort_t As[2][MT * 40];
    __shared__ ushort_t Bs[2][NT * 40];
    __shared__ uint_t smax[NT];
    int tid = threadIdx.x;
    int w = tid >> 6, lane = tid & 63;
    int quad = lane >> 4, l16 = lane & 15;
    int m0 = blockIdx.x * MT, n0 = blockIdx.y * NT;
    uint4_t pa[MT / 64], pb[NT / 64];
    auto prefetch = [&](int k0) {
#pragma unroll
        for (int rep = 0; rep < MT / 64; rep++) {
            int idx = tid + rep * 256;
            int row = idx >> 2, q = idx & 3;
            pa[rep] = *(const uint4_t*)(A + (size_t)(m0 + row) * lda + k0 + q * 8);
        }
#pragma unroll
        for (int rep = 0; rep < NT / 64; rep++) {
            int idx = tid + rep * 256;
            int row = idx >> 2, q = idx & 3;
            uint4_t v = {0, 0, 0, 0};
            if (n0 + row < Ndim) v = *(const uint4_t*)(W + (size_t)(n0 + row) * ldw + k0 + q * 8);
            pb[rep] = v;
        }
    };
    auto stage = [&](int buf) {
#pragma unroll
        for (int rep = 0; rep < MT / 64; rep++) {
            int idx = tid + rep * 256;
            int row = idx >> 2, q = idx & 3;
            *(uint4_t*)&As[buf][row * 40 + q * 8] = pa[rep];
        }
#pragma unroll
        for (int rep = 0; rep < NT / 64; rep++) {
            int idx = tid + rep * 256;
            int row = idx >> 2, q = idx & 3;
            *(uint4_t*)&Bs[buf][row * 40 + q * 8] = pb[rep];
        }
    };
    if (gmax) {
        for (int idx = tid; idx < NT; idx += 256) smax[idx] = 0u;
    }
    floatx4 acc[MTW][NTT] = {};
    prefetch(0);
    stage(0);
    __syncthreads();
    int cur = 0;
    for (int k0 = 0; k0 < K; k0 += 32) {
        bool more = (k0 + 32 < K);
        if (more) prefetch(k0 + 32);
        short8 ah[MTW];
#pragma unroll
        for (int mt = 0; mt < MTW; mt++) {
            int r = w * (MT / 4) + mt * 16 + l16;
            ah[mt] = *(short8*)&As[cur][r * 40 + quad * 8];
        }
#pragma unroll
        for (int nt = 0; nt < NTT; nt++) {
            int r = nt * 16 + l16;
            short8 bh = *(short8*)&Bs[cur][r * 40 + quad * 8];
#pragma unroll
            for (int mt = 0; mt < MTW; mt++)
                acc[mt][nt] = __builtin_amdgcn_mfma_f32_16x16x32_bf16(ah[mt], bh, acc[mt][nt], 0, 0, 0);
        }
        if (more) stage(cur ^ 1);
        __syncthreads();
        cur ^= 1;
    }
    if (lsm) {
#pragma unroll
        for (int mt = 0; mt < MTW; mt++) {
#pragma unroll
            for (int r = 0; r < 4; r++) {
                float vv[NTT];
                float mrow = -3e38f;
#pragma unroll
                for (int nt = 0; nt < NTT; nt++) {
                    int n = n0 + nt * 16 + l16;
                    float val = (n < Ndim) ? acc[mt][nt][r] + bias1[n] : -3e38f;
                    vv[nt] = val;
                    mrow = fmaxf(mrow, val);
                }
#pragma unroll
                for (int off = 8; off >= 1; off >>= 1)
                    mrow = fmaxf(mrow, __shfl_xor(mrow, off, 64));
                float s = 0.f;
#pragma unroll
                for (int nt = 0; nt < NTT; nt++)
                    if (vv[nt] > -1e38f) s += expf(vv[nt] - mrow);
#pragma unroll
                for (int off = 8; off >= 1; off >>= 1)
                    s += __shfl_xor(s, off, 64);
                float lse = mrow + logf(s);
                int m = m0 + w * (MT / 4) + mt * 16 + quad * 4 + r;
#pragma unroll
                for (int nt = 0; nt < NTT; nt++) {
                    int n = n0 + nt * 16 + l16;
                    if (n < Ndim) Cf[(size_t)m * ldc + n] = vv[nt] - lse;
                }
            }
        }
        return;
    }
    if (gmax) {
#pragma unroll
        for (int mt = 0; mt < MTW; mt++) {
#pragma unroll
            for (int nt = 0; nt < NTT; nt++) {
#pragma unroll
                for (int r = 0; r < 4; r++) {
                    float v = acc[mt][nt][r] + bias1[nt * 16 + l16 + n0];
                    atomicMax(&smax[nt * 16 + l16], fenc(v));
                }
            }
        }
        __syncthreads();
        for (int idx = tid; idx < NT; idx += 256)
            atomicMax(&gmax[n0 + idx], smax[idx]);
        return;
    }
#pragma unroll
    for (int mt = 0; mt < MTW; mt++) {
#pragma unroll
        for (int nt = 0; nt < NTT; nt++) {
#pragma unroll
            for (int r = 0; r < 4; r++) {
                int m = m0 + w * (MT / 4) + mt * 16 + quad * 4 + r;
                int n = n0 + nt * 16 + l16;
                if (n < Ndim) {
                    float v = acc[mt][nt][r];
                    if (bias1) v += bias1[n];
                    if (bias2) v += bias2[n];
                    if (relu && v < 0.f) v = 0.f;
                    if (Cf) Cf[(size_t)m * ldc + n] = v;
                    if (Ch) Ch[(size_t)m * ldh + n] = f2bs(v);
                }
            }
        }
    }
}

// ---------------- fused head tail: relu(bBh@mw3+mb3) -> bf16 LDS -> @mw4+mb4 -> lsm ----
// Identical numerics to the previous mw3->bCh->mw4 chain (same bf16 intermediate).
__global__ __launch_bounds__(256)
void k_head34(const ushort_t* __restrict__ A, int lda,
              const ushort_t* __restrict__ W3, int ldw3,
              const ushort_t* __restrict__ W4, int ldw4,
              const float* __restrict__ mb3, const float* __restrict__ mb4,
              float* __restrict__ out) {
    __shared__ ushort_t As[64 * 40];
    __shared__ ushort_t Bs[128 * 40];
    __shared__ ushort_t C1[64 * 136];   // bf16 intermediate, 16B-aligned rows
    int tid = threadIdx.x;
    int w = tid >> 6, lane = tid & 63;
    int quad = lane >> 4, l16 = lane & 15;
    int m0 = blockIdx.x * 64;
    // ---- phase 1: C1[64][128] = relu(A[64][256] @ W3^T + mb3), bf16 ----
    floatx4 acc[8] = {};
    for (int k0 = 0; k0 < 256; k0 += 32) {
        {
            int row = tid >> 2, q = tid & 3;
            *(uint4_t*)&As[row * 40 + q * 8] =
                *(const uint4_t*)(A + (size_t)(m0 + row) * lda + k0 + q * 8);
#pragma unroll
            for (int rep = 0; rep < 2; rep++) {
                int idx = tid + rep * 256;
                int br = idx >> 2, bq = idx & 3;
                *(uint4_t*)&Bs[br * 40 + bq * 8] =
                    *(const uint4_t*)(W3 + (size_t)br * ldw3 + k0 + bq * 8);
            }
        }
        __syncthreads();
        short8 ah = *(short8*)&As[(w * 16 + l16) * 40 + quad * 8];
#pragma unroll
        for (int nt = 0; nt < 8; nt++) {
            short8 bh = *(short8*)&Bs[(nt * 16 + l16) * 40 + quad * 8];
            acc[nt] = __builtin_amdgcn_mfma_f32_16x16x32_bf16(ah, bh, acc[nt], 0, 0, 0);
        }
        __syncthreads();
    }
#pragma unroll
    for (int nt = 0; nt < 8; nt++) {
#pragma unroll
        for (int r = 0; r < 4; r++) {
            int rowl = w * 16 + quad * 4 + r;
            int col = nt * 16 + l16;
            float v = acc[nt][r] + mb3[col];
            if (v < 0.f) v = 0.f;
            C1[rowl * 136 + col] = f2bs(v);
        }
    }
    __syncthreads();
    // ---- phase 2: out[64][50] = log_softmax(C1 @ W4^T + mb4) ----
    floatx4 acc2[4] = {};
    for (int k0 = 0; k0 < 128; k0 += 32) {
        {
            int row = tid >> 2, q = tid & 3;
            uint4_t v = {0, 0, 0, 0};
            if (row < 50) v = *(const uint4_t*)(W4 + (size_t)row * ldw4 + k0 + q * 8);
            *(uint4_t*)&Bs[row * 40 + q * 8] = v;
        }
        __syncthreads();
        short8 ah = *(short8*)&C1[(w * 16 + l16) * 136 + k0 + quad * 8];
#pragma unroll
        for (int nt = 0; nt < 4; nt++) {
            short8 bh = *(short8*)&Bs[(nt * 16 + l16) * 40 + quad * 8];
            acc2[nt] = __builtin_amdgcn_mfma_f32_16x16x32_bf16(ah, bh, acc2[nt], 0, 0, 0);
        }
        __syncthreads();
    }
#pragma unroll
    for (int r = 0; r < 4; r++) {
        float vv[4];
        float mrow = -3e38f;
#pragma unroll
        for (int nt = 0; nt < 4; nt++) {
            int n = nt * 16 + l16;
            float val = (n < 50) ? acc2[nt][r] + mb4[n] : -3e38f;
            vv[nt] = val;
            mrow = fmaxf(mrow, val);
        }
#pragma unroll
        for (int off = 8; off >= 1; off >>= 1)
            mrow = fmaxf(mrow, __shfl_xor(mrow, off, 64));
        float s = 0.f;
#pragma unroll
        for (int nt = 0; nt < 4; nt++)
            if (vv[nt] > -1e38f) s += expf(vv[nt] - mrow);
#pragma unroll
        for (int off = 8; off >= 1; off >>= 1)
            s += __shfl_xor(s, off, 64);
        float lse = mrow + logf(s);
        int m = m0 + w * 16 + quad * 4 + r;
#pragma unroll
        for (int nt = 0; nt < 4; nt++) {
            int n = nt * 16 + l16;
            if (n < 50) out[(size_t)m * 50 + n] = vv[nt] - lse;
        }
    }
}

// ---------------- split-bf16 (3-term) MFMA GEMM ----------------
__global__ __launch_bounds__(256)
void k_mgemm3(const ushort_t* __restrict__ Ah, const ushort_t* __restrict__ Al, int lda,
              const ushort_t* __restrict__ Wh, const ushort_t* __restrict__ Wl, int ldw,
              float* __restrict__ Cf, int ldc,
              int Ndim, int K) {
    constexpr int NTT = 4;
    __shared__ ushort_t AsH[64 * 40], BsH[64 * 40], AsL[64 * 40], BsL[64 * 40];
    int tid = threadIdx.x;
    int w = tid >> 6, lane = tid & 63;
    int quad = lane >> 4, l16 = lane & 15;
    int m0 = blockIdx.y * 64, n0 = blockIdx.x * 64;
    floatx4 acc[NTT] = {};
    for (int k0 = 0; k0 < K; k0 += 32) {
        {
            int row = tid >> 2, q = tid & 3;
            size_t go = (size_t)(m0 + row) * lda + k0 + q * 8;
            *(uint4_t*)&AsH[row * 40 + q * 8] = *(const uint4_t*)(Ah + go);
            *(uint4_t*)&AsL[row * 40 + q * 8] = *(const uint4_t*)(Al + go);
            uint4_t vh = {0, 0, 0, 0}, vl = {0, 0, 0, 0};
            size_t gw = (size_t)(n0 + row) * ldw + k0 + q * 8;
            if (n0 + row < Ndim) { vh = *(const uint4_t*)(Wh + gw); vl = *(const uint4_t*)(Wl + gw); }
            *(uint4_t*)&BsH[row * 40 + q * 8] = vh;
            *(uint4_t*)&BsL[row * 40 + q * 8] = vl;
        }
        __syncthreads();
        short8 ah, al;
        {
            int r = w * 16 + l16;
            ah = *(short8*)&AsH[r * 40 + quad * 8];
            al = *(short8*)&AsL[r * 40 + quad * 8];
        }
#pragma unroll
        for (int nt = 0; nt < NTT; nt++) {
            int r = nt * 16 + l16;
            short8 bh = *(short8*)&BsH[r * 40 + quad * 8];
            short8 bl = *(short8*)&BsL[r * 40 + quad * 8];
            acc[nt] = __builtin_amdgcn_mfma_f32_16x16x32_bf16(ah, bh, acc[nt], 0, 0, 0);
            acc[nt] = __builtin_amdgcn_mfma_f32_16x16x32_bf16(ah, bl, acc[nt], 0, 0, 0);
            acc[nt] = __builtin_amdgcn_mfma_f32_16x16x32_bf16(al, bh, acc[nt], 0, 0, 0);
        }
        __syncthreads();
    }
#pragma unroll
    for (int nt = 0; nt < NTT; nt++) {
#pragma unroll
        for (int r = 0; r < 4; r++) {
            int m = m0 + w * 16 + quad * 4 + r;
            int n = n0 + nt * 16 + l16;
            if (n < Ndim) Cf[(size_t)m * ldc + n] = acc[nt][r];
        }
    }
}

// ---------------- split-bf16 MFMA pairwise distances -> packed sort keys -----------
// keys stored through cache (L3-resident for the immediately-following k_topk read).
__global__ __launch_bounds__(256)
void k_mdist(const ushort_t* __restrict__ Lh, const ushort_t* __restrict__ Ll,
             int co, int C, uint_t* __restrict__ keys) {
    __shared__ ushort_t AsH[128 * 40], AsL[128 * 40], BsH[64 * 40], BsL[64 * 40];
    __shared__ float sqa[128], sqb[64];
    int tid = threadIdx.x;
    int w = tid >> 6, lane = tid & 63;
    int quad = lane >> 4, l16 = lane & 15;
    int b = blockIdx.z, cb = b * PP;
    int i0 = blockIdx.y * 128, j0 = blockIdx.x * 64;
    floatx4 acc[2][4] = {};
    float sacc = 0.f;
    for (int k0 = 0; k0 < C; k0 += 32) {
#pragma unroll
        for (int rep = 0; rep < 8; rep++) {
            int d = tid + rep * 256;
            int row = d >> 4, c2 = d & 15;
            size_t gi = ((size_t)(cb + i0 + row) * LDH + co + k0 + c2 * 2) >> 1;
            *(uint_t*)&AsH[row * 40 + c2 * 2] = ((const uint_t*)Lh)[gi];
            *(uint_t*)&AsL[row * 40 + c2 * 2] = ((const uint_t*)Ll)[gi];
        }
#pragma unroll
        for (int rep = 0; rep < 4; rep++) {
            int d = tid + rep * 256;
            int row = d >> 4, c2 = d & 15;
            size_t gi = ((size_t)(cb + j0 + row) * LDH + co + k0 + c2 * 2) >> 1;
            *(uint_t*)&BsH[row * 40 + c2 * 2] = ((const uint_t*)Lh)[gi];
            *(uint_t*)&BsL[row * 40 + c2 * 2] = ((const uint_t*)Ll)[gi];
        }
        __syncthreads();
        if (tid < 128) {
#pragma unroll
            for (int kk = 0; kk < 16; kk++) {
                uint_t ph = *(uint_t*)&AsH[tid * 40 + kk * 2];
                uint_t pl = *(uint_t*)&AsL[tid * 40 + kk * 2];
                float v0 = bs2f((ushort_t)(ph & 0xFFFFu)) + bs2f((ushort_t)(pl & 0xFFFFu));
                sacc += v0 * v0;
                float v1 = bs2f((ushort_t)(ph >> 16)) + bs2f((ushort_t)(pl >> 16));
                sacc += v1 * v1;
            }
        } else if (tid < 192) {
            int row = tid - 128;
#pragma unroll
            for (int kk = 0; kk < 16; kk++) {
                uint_t ph = *(uint_t*)&BsH[row * 40 + kk * 2];
                uint_t pl = *(uint_t*)&BsL[row * 40 + kk * 2];
                float v0 = bs2f((ushort_t)(ph & 0xFFFFu)) + bs2f((ushort_t)(pl & 0xFFFFu));
                sacc += v0 * v0;
                float v1 = bs2f((ushort_t)(ph >> 16)) + bs2f((ushort_t)(pl >> 16));
                sacc += v1 * v1;
            }
        }
        short8 ah[2], al[2];
#pragma unroll
        for (int mt = 0; mt < 2; mt++) {
            int r = w * 32 + mt * 16 + l16;
            ah[mt] = *(short8*)&AsH[r * 40 + quad * 8];
            al[mt] = *(short8*)&AsL[r * 40 + quad * 8];
        }
#pragma unroll
        for (int nt = 0; nt < 4; nt++) {
            int r = nt * 16 + l16;
            short8 bh = *(short8*)&BsH[r * 40 + quad * 8];
            short8 bl = *(short8*)&BsL[r * 40 + quad * 8];
#pragma unroll
            for (int mt = 0; mt < 2; mt++) {
                acc[mt][nt] = __builtin_amdgcn_mfma_f32_16x16x32_bf16(ah[mt], bh, acc[mt][nt], 0, 0, 0);
                acc[mt][nt] = __builtin_amdgcn_mfma_f32_16x16x32_bf16(ah[mt], bl, acc[mt][nt], 0, 0, 0);
                acc[mt][nt] = __builtin_amdgcn_mfma_f32_16x16x32_bf16(al[mt], bh, acc[mt][nt], 0, 0, 0);
            }
        }
        __syncthreads();
    }
    if (tid < 128) sqa[tid] = sacc;
    else if (tid < 192) sqb[tid - 128] = sacc;
    __syncthreads();
#pragma unroll
    for (int mt = 0; mt < 2; mt++) {
#pragma unroll
        for (int nt = 0; nt < 4; nt++) {
#pragma unroll
            for (int r = 0; r < 4; r++) {
                int li = w * 32 + mt * 16 + quad * 4 + r;
                int lj = nt * 16 + l16;
                int il = i0 + li, jl = j0 + lj;
                float dd = sqa[li] + sqb[lj] - 2.f * acc[mt][nt][r];
                dd = (il == jl) ? 3e9f : fmaxf(dd, 0.f);
                uint_t key = (__float_as_uint(dd) & 0xFFFFF800u) | (uint_t)jl;
                keys[(size_t)(cb + il) * PP + jl] = key;
            }
        }
    }
}

// ---------------- top-30 smallest per row via packed u32 keys ----------------
__global__ __launch_bounds__(256)
void k_topk(const uint_t* __restrict__ keys, int* __restrict__ nbr) {
    int r = blockIdx.x * 4 + (threadIdx.x >> 6);
    int lane = threadIdx.x & 63;
    int base = (r / PP) * PP;
    const uint_t* row = keys + (size_t)r * PP;
    uint_t v[32];
#pragma unroll
    for (int j = 0; j < 8; j++)
        *(uint4_t*)&v[j * 4] = *(const uint4_t*)(row + lane * 4 + j * 256);
    uint_t g[8];
#pragma unroll
    for (int j = 0; j < 8; j++)
        g[j] = min(min(v[j * 4], v[j * 4 + 1]), min(v[j * 4 + 2], v[j * 4 + 3]));
    uint_t lv = g[0];
#pragma unroll
    for (int j = 1; j < 8; j++) lv = min(lv, g[j]);
    for (int sel = 0; sel < KNN; sel++) {
        uint_t bk = lv;
#pragma unroll
        for (int off = 32; off > 0; off >>= 1)
            bk = min(bk, (uint_t)__shfl_xor((int)bk, off, 64));
        uint_t bks = __builtin_amdgcn_readfirstlane(bk);
        if (lane == 0) nbr[r * KTOT + sel] = base + (int)(bks & 0x7FFu);
        int grp = (int)((bks & 0x7FFu) >> 8);
#pragma unroll
        for (int jj = 0; jj < 8; jj++)
            if (grp == jj) {
#pragma unroll
                for (int t = 0; t < 4; t++)
                    v[jj * 4 + t] = (v[jj * 4 + t] == bks) ? 0xFFFFFFFFu : v[jj * 4 + t];
                g[jj] = min(min(v[jj * 4], v[jj * 4 + 1]), min(v[jj * 4 + 2], v[jj * 4 + 3]));
            }
        lv = g[0];
#pragma unroll
        for (int j = 1; j < 8; j++) lv = min(lv, g[j]);
    }
    if (lane == 0) nbr[r * KTOT + KNN] = r;
}

// ---------------- GAT edge-softmax + aggregate, fp32 z (stages 1-2) ----------------
// z row: [3F proj | 3 src-scores | 3 dst-scores].  NN nodes/block, 192 threads.
template<int F, int NN>
__global__ __launch_bounds__(192)
void k_gat2(const float* __restrict__ z, int ldz,
            const int* __restrict__ nbr,
            const float* __restrict__ bc,
            ushort_t* __restrict__ dh, ushort_t* __restrict__ dl) {
    constexpr int TPN = 3 * F / 4;   // threads per node in aggregate (48 or 96)
    __shared__ int srcs[NN][KTOT];
    __shared__ float alpha[NN][96];
    __shared__ float part[NN][2][F];
    int tid = threadIdx.x;
    if (tid < NN * KTOT) {
        int u = tid / KTOT, k = tid % KTOT;
        int t = blockIdx.x * NN + u;
        int node = (t & 3) * PP + (t >> 2);
        srcs[u][k] = nbr[node * KTOT + k];
    }
    __syncthreads();
#pragma unroll
    for (int u2 = 0; u2 < NN; u2 += 2) {
        int u = u2 + tid / 96;       // 2 nodes per 192-thread pass; 32-lane aligned groups
        int r = tid % 96, h = r >> 5, k = r & 31;
        int t = blockIdx.x * NN + u;
        int node = (t & 3) * PP + (t >> 2);
        float e = -3e38f;
        if (k < KTOT) {
            float sv = z[(size_t)srcs[u][k] * ldz + 3 * F + h];
            float tv = z[(size_t)node * ldz + 3 * F + 3 + h];
            e = sv + tv;
            if (e < 0.f) e *= 0.2f;
        }
        float m = e;
#pragma unroll
        for (int off = 16; off >= 1; off >>= 1)
            m = fmaxf(m, __shfl_xor(m, off, 32));
        float ex = (k < KTOT) ? expf(e - m) : 0.f;
        float s = ex;
#pragma unroll
        for (int off = 16; off >= 1; off >>= 1)
            s += __shfl_xor(s, off, 32);
        alpha[u][h * 32 + k] = ex / s;
    }
    __syncthreads();
    // aggregate: thread -> (u, h, j-quad); float4 gathers, 2 vector accumulators
    {
        int u = tid / TPN, r = tid % TPN;
        int h = r / (F / 4), jq = r % (F / 4);
        const float* zb = z + h * F + jq * 4;
        floatx4 a0 = {0.f, 0.f, 0.f, 0.f}, a1 = {0.f, 0.f, 0.f, 0.f};
#pragma unroll
        for (int k = 0; k < KTOT; k += 2) {
            float a = alpha[u][h * 32 + k];
            floatx4 p = *(const floatx4*)(zb + (size_t)srcs[u][k] * ldz);
            a0 += p * a;
            if (k + 1 < KTOT) {
                float a2 = alpha[u][h * 32 + k + 1];
                floatx4 p2 = *(const floatx4*)(zb + (size_t)srcs[u][k + 1] * ldz);
                a1 += p2 * a2;
            }
        }
        floatx4 av = a0 + a1;
        if (h > 0)
            *(floatx4*)&part[u][h - 1][jq * 4] = av;
        __syncthreads();
        if (h == 0) {
            int t = blockIdx.x * NN + u;
            int node = (t & 3) * PP + (t >> 2);
            int j0 = jq * 4;
            floatx4 p0 = *(const floatx4*)&part[u][0][j0];
            floatx4 p1 = *(const floatx4*)&part[u][1][j0];
            floatx4 bcv = *(const floatx4*)&bc[j0];
            floatx4 v = av + p0 + p1 + bcv;
            ushort_t hh[4], ll[4];
#pragma unroll
            for (int q = 0; q < 4; q++) split2(v[q], hh[q], ll[q]);
            *(uint_t*)&dh[(size_t)node * LDH + j0] = (uint_t)hh[0] | ((uint_t)hh[1] << 16);
            *(uint_t*)&dh[(size_t)node * LDH + j0 + 2] = (uint_t)hh[2] | ((uint_t)hh[3] << 16);
            if (dl) {
                *(uint_t*)&dl[(size_t)node * LDH + j0] = (uint_t)ll[0] | ((uint_t)ll[1] << 16);
                *(uint_t*)&dl[(size_t)node * LDH + j0 + 2] = (uint_t)ll[2] | ((uint_t)ll[3] << 16);
            }
        }
    }
}

// ---------------- GAT edge-softmax + aggregate, bf16 z (stages 3-4) ----------------
// z stored bf16 -> half the gather bytes.  Thread owns (node, head, j-oct):
// short8 gathers (16B = 8 cols), 8 independent FMA chains.  All 192 threads active.
template<int F, int NN>
__global__ __launch_bounds__(192)
void k_gat2b(const ushort_t* __restrict__ z, int ldz,
             const int* __restrict__ nbr,
             const float* __restrict__ bc,
             ushort_t* __restrict__ dh) {
    constexpr int TPN = 3 * F / 8;   // 24 (F=64, NN=8) or 48 (F=128, NN=4)
    __shared__ int srcs[NN][KTOT];
    __shared__ float alpha[NN][96];
    __shared__ float part[NN][2][F];
    int tid = threadIdx.x;
    for (int idx = tid; idx < NN * KTOT; idx += 192) {
        int u = idx / KTOT, k = idx % KTOT;
        int t = blockIdx.x * NN + u;
        int node = (t & 3) * PP + (t >> 2);
        srcs[u][k] = nbr[node * KTOT + k];
    }
    __syncthreads();
#pragma unroll
    for (int u2 = 0; u2 < NN; u2 += 2) {
        int u = u2 + tid / 96;
        int r = tid % 96, h = r >> 5, k = r & 31;
        int t = blockIdx.x * NN + u;
        int node = (t & 3) * PP + (t >> 2);
        float e = -3e38f;
        if (k < KTOT) {
            float sv = bs2f(z[(size_t)srcs[u][k] * ldz + 3 * F + h]);
            float tv = bs2f(z[(size_t)node * ldz + 3 * F + 3 + h]);
            e = sv + tv;
            if (e < 0.f) e *= 0.2f;
        }
        float m = e;
#pragma unroll
        for (int off = 16; off >= 1; off >>= 1)
            m = fmaxf(m, __shfl_xor(m, off, 32));
        float ex = (k < KTOT) ? expf(e - m) : 0.f;
        float s = ex;
#pragma unroll
        for (int off = 16; off >= 1; off >>= 1)
            s += __shfl_xor(s, off, 32);
        alpha[u][h * 32 + k] = ex / s;
    }
    __syncthreads();
    {
        int u = tid / TPN, r = tid % TPN;
        int h = r / (F / 8), jo = r % (F / 8);
        const ushort_t* zb = z + h * F + jo * 8;
        float a[8] = {};
        for (int k = 0; k < KTOT; k++) {
            float al = alpha[u][h * 32 + k];
            short8 v = *(const short8*)(zb + (size_t)srcs[u][k] * ldz);
#pragma unroll
            for (int q = 0; q < 8; q++)
                a[q] += al * bs2f((ushort_t)v[q]);
        }
        if (h > 0) {
#pragma unroll
            for (int q = 0; q < 8; q++) part[u][h - 1][jo * 8 + q] = a[q];
        }
        __syncthreads();
        if (h == 0) {
            int t = blockIdx.x * NN + u;
            int node = (t & 3) * PP + (t >> 2);
            int j0 = jo * 8;
#pragma unroll
            for (int q2 = 0; q2 < 4; q2++) {
                float v0 = a[q2 * 2] + part[u][0][j0 + q2 * 2] + part[u][1][j0 + q2 * 2] + bc[j0 + q2 * 2];
                float v1 = a[q2 * 2 + 1] + part[u][0][j0 + q2 * 2 + 1] + part[u][1][j0 + q2 * 2 + 1] + bc[j0 + q2 * 2 + 1];
                *(uint_t*)&dh[(size_t)node * LDH + j0 + q2 * 2] =
                    (uint_t)f2bs(v0) | ((uint_t)f2bs(v1) << 16);
            }
        }
    }
}

// ---------------- gproj: decode fused column max + split-K matmul ----------------
__global__ void k_gproj(const uint_t* __restrict__ genc,
                        const float* __restrict__ mw1,
                        const float* __restrict__ mb1,
                        float* __restrict__ gproj) {
    __shared__ float gs[128];
    int kb = blockIdx.x;           // 8 blocks x 128 k
    int t = threadIdx.x;           // 256
    if (t < 128) gs[t] = fdec(genc[kb * 128 + t]);
    __syncthreads();
    float acc = (kb == 0) ? mb1[t] : 0.f;
    for (int k = 0; k < 128; k++)
        acc += gs[k] * mw1[(size_t)(326 + kb * 128 + k) * 256 + t];
    atomicAdd(&gproj[t], acc);
}

// ---------------- host side ----------------
struct WT { ushort_t *h, *l; int kp; };

extern "C" void kernel_launch(void* const* d_in, const int* in_sizes, int n_in,
                              void* d_out, int out_size, void* d_ws, size_t ws_size,
                              hipStream_t stream) {
    (void)in_sizes; (void)n_in; (void)out_size; (void)ws_size;
    const float* x    = (const float*)d_in[0];
    const float* pos  = (const float*)d_in[1];
    const float* w1   = (const float*)d_in[3];
    const float* as1  = (const float*)d_in[4];
    const float* ad1  = (const float*)d_in[5];
    const float* b1   = (const float*)d_in[6];
    const float* ml1w = (const float*)d_in[7];
    const float* ml1b = (const float*)d_in[8];
    const float* w2   = (const float*)d_in[9];
    const float* as2  = (const float*)d_in[10];
    const float* ad2  = (const float*)d_in[11];
    const float* b2   = (const float*)d_in[12];
    const float* ml2w = (const float*)d_in[13];
    const float* ml2b = (const float*)d_in[14];
    const float* w3   = (const float*)d_in[15];
    const float* as3  = (const float*)d_in[16];
    const float* ad3  = (const float*)d_in[17];
    const float* b3   = (const float*)d_in[18];
    const float* ml3w = (const float*)d_in[19];
    const float* ml3b = (const float*)d_in[20];
    const float* w4   = (const float*)d_in[21];
    const float* as4  = (const float*)d_in[22];
    const float* ad4  = (const float*)d_in[23];
    const float* b4   = (const float*)d_in[24];
    const float* ml4w = (const float*)d_in[25];
    const float* ml4b = (const float*)d_in[26];
    const float* few1 = (const float*)d_in[27];
    const float* feb1 = (const float*)d_in[28];
    const float* few2 = (const float*)d_in[29];
    const float* feb2 = (const float*)d_in[30];
    const float* mw1  = (const float*)d_in[31];
    const float* mb1  = (const float*)d_in[32];
    const float* mw2  = (const float*)d_in[33];
    const float* mb2  = (const float*)d_in[34];
    const float* mw3  = (const float*)d_in[35];
    const float* mb3  = (const float*)d_in[36];
    const float* mw4  = (const float*)d_in[37];
    const float* mb4  = (const float*)d_in[38];

    float* Wb = (float*)d_ws;
    size_t off = 0;
    auto alloc = [&](size_t n) { float* p = Wb + off; off += (n + 63) & ~(size_t)63; return p; };

    float*    dist = alloc((size_t)NPTS * PP);                  // 67 MB aliased region
    ushort_t* l4h  = (ushort_t*)alloc((size_t)NPTS * LDH / 2);
    ushort_t* l4l  = (ushort_t*)alloc((size_t)NPTS * LDH / 2);
    // genc|gproj|bcp contiguous with l4 planes -> single memset covers all
    uint_t* genc = (uint_t*)alloc(1024);                        // encoded col maxima
    float* gproj = alloc(256);
    float* bcp = alloc(320);                                    // bc1|bc2|bc3|bc4
    float* bc1 = bcp, *bc2 = bcp + 64, *bc3 = bcp + 128, *bc4 = bcp + 192;
    int*   nbr   = (int*)alloc((size_t)NPTS * KTOT);
    ushort_t* wtpool = (ushort_t*)alloc(1742336);
    float* wc1 = alloc(6 * 198);
    float* wc2 = alloc(70 * 198);
    float* wc3 = alloc(134 * 198);
    float* wc4 = alloc(198 * 390);

    // aliases inside dist region (disjoint lifetimes):
    //   dkey lives between k_mdist and k_topk; z/zb written AFTER topk consumed keys,
    //   dead before next k_mdist; hah/bAh/bBh live in the fe/head phase only.
    char* d0 = (char*)dist;
    uint_t*   dkey = (uint_t*)dist;
    float*    z    = dist;
    ushort_t* zb   = (ushort_t*)dist;                           // bf16 z (stages 3-4)
    ushort_t* hah  = (ushort_t*)d0;                             // fe1 out hi (16.8MB)
    ushort_t* bBh  = (ushort_t*)(d0 + (size_t)NPTS * 1024 * 2); // mw2 out hi
    ushort_t* bAh = (ushort_t*)d0;                              // mw1 out hi (hah dead)

    // ---- zero link4 planes + accumulators (one contiguous memset) ----
    hipMemsetAsync(l4h, 0, ((size_t)NPTS * LDH + 1600) * 4, stream); // l4h|l4l|genc|gproj|bcp

    // ---- combined GAT weights (ml-proj + scores folded into producing GEMM) ----
    {
        CAll ca;
        const float* ws_[4] = {w1, w2, w3, w4};
        const float* mlws[4] = {ml1w, ml2w, ml3w, ml4w};
        const float* ass[4] = {as1, as2, as3, as4};
        const float* ads[4] = {ad1, ad2, ad3, ad4};
        const float* bs_[4] = {b1, b2, b3, b4};
        const float* mlbs[4] = {ml1b, ml2b, ml3b, ml4b};
        float* wcs[4] = {wc1, wc2, wc3, wc4};
        float* bcs[4] = {bc1, bc2, bc3, bc4};
        int Ks[4] = {6, 70, 134, 198};
        int t = 0;
        for (int i = 0; i < 4; i++) {
            ca.w[i] = ws_[i]; ca.mlw[i] = mlws[i]; ca.as_[i] = ass[i]; ca.ad[i] = ads[i];
            ca.b[i] = bs_[i]; ca.mlb[i] = mlbs[i]; ca.wc[i] = wcs[i]; ca.bc[i] = bcs[i];
            ca.K[i] = Ks[i];
            if (i < 3) { ca.t0[i] = t; t += ((Ks[i] + 7) / 8) * 3; }
        }
        ca.t64 = t;
        int total = t + 25 * 3;   // + F=128 blocks (K=198 -> 25 slabs x 3 heads)
        k_combine_all<<<total, 128, 0, stream>>>(ca);
    }

    // ---- fused weight transpose+split (MFMA weights; combined ones from wc*) ----
    WArgs wa;
    WT wt[NSEG];
    {
        const float* srcs[NSEG] = {wc2, wc3, wc4, few1, few2, mw1, mw2, mw3, mw4};
        int Ks[NSEG] = {70, 134, 198, 326, 1024, 326, 256, 256, 128};
        int Ns[NSEG] = {198, 198, 390, 1024, 1024, 256, 256, 128, 50};
        size_t wo = 0; int tiles = 0;
        for (int i = 0; i < NSEG; i++) {
            int kp = (Ks[i] + 31) & ~31;
            wa.src[i] = srcs[i];
            wa.dst[i] = wtpool + wo;
            wa.K[i] = Ks[i]; wa.N[i] = Ns[i]; wa.Kp[i] = kp;
            wa.t0[i] = tiles;
            wt[i] = { wtpool + wo, wtpool + wo + (size_t)kp * Ns[i], kp };
            wo += (size_t)2 * kp * Ns[i];
            tiles += (kp / 32) * ((Ns[i] + 31) / 32);
        }
        k_wsplit_all<<<tiles, 256, 0, stream>>>(wa);
    }
    WT tw2 = wt[0], tw3 = wt[1], tw4 = wt[2], tfe1 = wt[3], tfe2 = wt[4],
       tmw1 = wt[5], tmw2 = wt[6], tmw3 = wt[7], tmw4 = wt[8];

    auto mg3 = [&](const ushort_t* Ah, const ushort_t* Al, int lda, WT t,
                   float* Cf, int ldc, int Nd, int K) {
        dim3 g((Nd + 63) / 64, NPTS / 64);
        k_mgemm3<<<g, 256, 0, stream>>>(Ah, Al, lda, t.h, t.l, t.kp, Cf, ldc, Nd, K);
    };
    auto mg1 = [&](int MT, int NT, const ushort_t* Ah, int lda, WT t,
                   float* Cf, int ldc, ushort_t* Ch, int ldhh,
                   int Nd, int K, const float* bb1, const float* bb2,
                   int relu, int lsm, uint_t* gmax) {
        dim3 g(NPTS / MT, (Nd + NT - 1) / NT);
        if (MT == 128 && NT == 128)
            k_mgemm1<128, 128><<<g, 256, 0, stream>>>(Ah, lda, t.h, t.kp, Cf, ldc, Ch, ldhh, Nd, K,
                bb1, bb2, relu, lsm, gmax);
        else if (MT == 128)
            k_mgemm1<128, 64><<<g, 256, 0, stream>>>(Ah, lda, t.h, t.kp, Cf, ldc, Ch, ldhh, Nd, K,
                bb1, bb2, relu, lsm, gmax);
        else
            k_mgemm1<64, 64><<<g, 256, 0, stream>>>(Ah, lda, t.h, t.kp, Cf, ldc, Ch, ldhh, Nd, K,
                bb1, bb2, relu, lsm, gmax);
    };

    dim3 dgrid(PP / 64, PP / 128, 4);
    k_build_x0<<<(NPTS * 6 + 255) / 256, 256, 0, stream>>>(x, pos, l4h, l4l);

    // ---- stage 1: knn on x0 (C=6; cols 6..31 still zero); tw1 AFTER topk; gat -> x1 ----
    k_mdist<<<dgrid, 256, 0, stream>>>(l4h, l4l, 0, 6, dkey);
    k_topk<<<NPTS / 4, 256, 0, stream>>>(dkey, nbr);
    k_tw1<<<(NPTS * 198 + 255) / 256, 256, 0, stream>>>(x, pos, wc1, z);
    k_gat2<64, 4><<<NPTS / 4, 192, 0, stream>>>(z, LDZ, nbr, bc1, l4h + 6, l4l + 6);

    // ---- stage 2: knn on x1 (C=64); split-bf16 GEMM -> z2 (proj+scores); gat -> x2 ----
    k_mdist<<<dgrid, 256, 0, stream>>>(l4h, l4l, 6, 64, dkey);
    k_topk<<<NPTS / 4, 256, 0, stream>>>(dkey, nbr);
    mg3(l4h, l4l, LDH, tw2, z, LDZ, 198, 70);
    k_gat2<64, 4><<<NPTS / 4, 192, 0, stream>>>(z, LDZ, nbr, bc2, l4h + 70, l4l + 70);

    // ---- stage 3: knn on x2 (C=64); hi-only GEMM -> zb3 (bf16); gat -> x3 (hi only) ----
    k_mdist<<<dgrid, 256, 0, stream>>>(l4h, l4l, 70, 64, dkey);
    k_topk<<<NPTS / 4, 256, 0, stream>>>(dkey, nbr);
    mg1(128, 64, l4h, LDH, tw3, nullptr, 0, zb, LDZB3, 198, 134, nullptr, nullptr, 0, 0, nullptr);
    k_gat2b<64, 8><<<NPTS / 8, 192, 0, stream>>>(zb, LDZB3, nbr, bc3, l4h + 134);

    // ---- stage 4 (reuses stage-3 nbr): GEMM -> zb4 (bf16); gat(F=128) -> x4 (hi only) ----
    mg1(128, 64, l4h, LDH, tw4, nullptr, 0, zb, LDZB4, 390, 198, nullptr, nullptr, 0, 0, nullptr);
    k_gat2b<128, 4><<<NPTS / 4, 192, 0, stream>>>(zb, LDZB4, nbr, bc4, l4h + 198);

    // ---- fe_mlp: fe1 -> bf16 acts; fe2 -> fused global column max (no C write) ----
    mg1(128, 128, l4h, LDH, tfe1, nullptr, 0, hah, 1024, 1024, 326, feb1, nullptr, 1, 0, nullptr);
    mg1(128, 128, hah, 1024, tfe2, nullptr, 0, nullptr, 0, 1024, 1024, feb2, nullptr, 0, 0, genc);
    k_gproj<<<8, 256, 0, stream>>>(genc, mw1, mb1, gproj);

    // ---- head (bf16 tier; mw3+mw4 fused, log_softmax writes d_out) ----
    mg1(128, 64, l4h, LDH, tmw1, nullptr, 0, bAh, 256, 256, 326, nullptr, gproj, 1, 0, nullptr);
    mg1(128, 64, bAh, 256, tmw2, nullptr, 0, bBh, 256, 256, 256, mb2, nullptr, 1, 0, nullptr);
    k_head34<<<NPTS / 64, 256, 0, stream>>>(bBh, 256, tmw3.h, tmw3.kp, tmw4.h, tmw4.kp,
                                            mb3, mb4, (float*)d_out);
}

// Round 12
// 496.111 us; speedup vs baseline: 1.1088x; 1.0158x over previous
//
#include <hip/hip_runtime.h>
#include <hip/hip_bf16.h>
#include <hip/amd_detail/amd_hip_vector_types.h>

#define NPTS 8192
#define PP 2048
#define KNN 30
#define KTOT 31
#define HEADS 3
#define LDH 352   // padded ld for link4 hi/lo (bf16): >= Kpad32(326), mult of 8
#define NSEG 9
#define LDZ 200   // z ld stages 1-2 (fp32): 198 cols = 192 proj + 3 s + 3 t
#define LDZB3 200 // z ld stage 3 (bf16 ushorts)
#define LDZB4 392 // z ld stage 4 (bf16 ushorts): 390 cols = 384 proj + 3 s + 3 t

typedef __attribute__((ext_vector_type(8))) short short8;
typedef __attribute__((ext_vector_type(4))) float floatx4;
typedef __attribute__((ext_vector_type(4))) unsigned int uint4_t;
typedef unsigned short ushort_t;
typedef unsigned int uint_t;

__device__ inline ushort_t f2bs(float v) {
    __hip_bfloat16 b = __float2bfloat16(v);
    return *reinterpret_cast<ushort_t*>(&b);
}
__device__ inline float bs2f(ushort_t u) {
    __hip_bfloat16 b = *reinterpret_cast<__hip_bfloat16*>(&u);
    return __bfloat162float(b);
}
__device__ inline void split2(float v, ushort_t& h, ushort_t& l) {
    h = f2bs(v);
    l = f2bs(v - bs2f(h));
}
// order-preserving fp32 <-> uint mapping for atomic max
__device__ inline uint_t fenc(float f) {
    uint_t b = __float_as_uint(f);
    return (b & 0x80000000u) ? ~b : (b | 0x80000000u);
}
__device__ inline float fdec(uint_t e) {
    return __uint_as_float((e & 0x80000000u) ? (e & 0x7FFFFFFFu) : ~e);
}

// ---------------- build x0 (hi/lo) into link4 cols 0..5 ----------------
__global__ void k_build_x0(const float* __restrict__ x, const float* __restrict__ pos,
                           ushort_t* __restrict__ lh, ushort_t* __restrict__ ll) {
    int i = blockIdx.x * blockDim.x + threadIdx.x;
    if (i >= NPTS * 6) return;
    int n = i / 6, c = i % 6;
    float v = (c < 3) ? x[n * 3 + c] : pos[n * 3 + (c - 3)];
    ushort_t h, l; split2(v, h, l);
    lh[(size_t)n * LDH + c] = h;
    ll[(size_t)n * LDH + c] = l;
}

// ---------------- combined GAT weights: Wc = [W*blkdiag(mlW) | W*a_src | W*a_dst],
//                  bc = b*blkdiag(mlW) + mlb  (per stage, exact fp32) ----------------
template<int F_>
__device__ inline void combine_body(const float* __restrict__ w, const float* __restrict__ mlw,
                                    const float* __restrict__ as_, const float* __restrict__ ad,
                                    const float* __restrict__ b, const float* __restrict__ mlb,
                                    float* __restrict__ wc, float* __restrict__ bc,
                                    int K_, int lb) {
    constexpr int NC = 3 * F_ + 6;
    constexpr int JG = 128 / F_;   // row-groups (2 for F=64, 1 for F=128)
    constexpr int RG = 8 / JG;     // rows per thread
    int h = lb % 3, kb = lb / 3;
    int k0 = kb * 8, KS = min(8, K_ - k0);
    int tid = threadIdx.x;
    int j = tid % F_, rg = tid / F_;
    __shared__ float ws[8][F_];
    __shared__ float ms[32][F_];
    __shared__ float bav[3][F_];
    for (int idx = tid; idx < 8 * F_; idx += 128) {
        int r = idx / F_, f = idx % F_;
        ws[r][f] = (r < KS) ? w[(size_t)(k0 + r) * (3 * F_) + h * F_ + f] : 0.f;
    }
    for (int f = tid; f < F_; f += 128) {
        bav[0][f] = b[h * F_ + f];
        bav[1][f] = as_[h * F_ + f];
        bav[2][f] = ad[h * F_ + f];
    }
    __syncthreads();
    const float* mh = mlw + (size_t)h * F_ * F_;
    float acc[RG] = {};
    float bacc = 0.f;
    for (int f0 = 0; f0 < F_; f0 += 32) {
        for (int idx = tid; idx < 32 * F_; idx += 128) {
            int u = idx / F_, jj = idx % F_;
            ms[u][jj] = mh[(size_t)(f0 + u) * F_ + jj];
        }
        __syncthreads();
#pragma unroll
        for (int u = 0; u < 32; u++) {
            float m = ms[u][j];
#pragma unroll
            for (int r = 0; r < RG; r++)
                acc[r] += ws[rg * RG + r][f0 + u] * m;
            if (rg == 0) bacc += bav[0][f0 + u] * m;
        }
        __syncthreads();
    }
#pragma unroll
    for (int r = 0; r < RG; r++) {
        int k = k0 + rg * RG + r;
        if (k < K_) wc[(size_t)k * NC + h * F_ + j] = acc[r];
    }
    if (kb == 0 && rg == 0)
        atomicAdd(&bc[j], bacc + (h == 0 ? mlb[j] : 0.f));
    // score columns: threads (r, src/dst) from staged w-slab (LDS, unrolled)
    if (tid < 16) {
        int r = tid >> 1, sc = tid & 1;
        if (r < KS) {
            float s = 0.f;
#pragma unroll
            for (int f = 0; f < F_; f++) s += ws[r][f] * bav[1 + sc][f];
            wc[(size_t)(k0 + r) * NC + 3 * F_ + sc * 3 + h] = s;
        }
    }
}

struct CAll {
    const float *w[4], *mlw[4], *as_[4], *ad[4], *b[4], *mlb[4];
    float *wc[4], *bc[4];
    int K[4], t0[4], t64;
};
__global__ __launch_bounds__(128)
void k_combine_all(CAll a) {
    int bt = blockIdx.x;
    if (bt < a.t64) {
        int si = 0;
#pragma unroll
        for (int i = 1; i < 3; i++) if (bt >= a.t0[i]) si = i;
        combine_body<64>(a.w[si], a.mlw[si], a.as_[si], a.ad[si], a.b[si], a.mlb[si],
                         a.wc[si], a.bc[si], a.K[si], bt - a.t0[si]);
    } else {
        combine_body<128>(a.w[3], a.mlw[3], a.as_[3], a.ad[3], a.b[3], a.mlb[3],
                          a.wc[3], a.bc[3], a.K[3], bt - a.t64);
    }
}

// ---------------- tw1: z = [x|pos] @ Wc1, exact fp32 (K=6, N=198) ----------------
// NOTE: z aliases the dist/key region -> must run AFTER k_topk consumed the keys.
__global__ void k_tw1(const float* __restrict__ x, const float* __restrict__ pos,
                      const float* __restrict__ wc, float* __restrict__ z) {
    int t = blockIdx.x * blockDim.x + threadIdx.x;
    if (t >= NPTS * 198) return;
    int n = t / 198, j = t % 198;
    float acc = 0.f;
#pragma unroll
    for (int c = 0; c < 3; c++) {
        acc += x[n * 3 + c] * wc[c * 198 + j];
        acc += pos[n * 3 + c] * wc[(3 + c) * 198 + j];
    }
    z[(size_t)n * LDZ + j] = acc;
}

// ---------------- fused weight transpose + split (MFMA weights, one launch) ----------
struct WArgs {
    const float* src[NSEG];
    ushort_t* dst[NSEG];
    int K[NSEG], N[NSEG], Kp[NSEG], t0[NSEG];
};
__global__ void k_wsplit_all(WArgs a) {
    int bt = blockIdx.x;
    int si = 0;
#pragma unroll
    for (int i = 1; i < NSEG; i++) if (bt >= a.t0[i]) si = i;
    int t = bt - a.t0[si];
    int K_ = a.K[si], N_ = a.N[si], Kp = a.Kp[si];
    const float* src = a.src[si];
    ushort_t* dh = a.dst[si];
    ushort_t* dl = dh + (size_t)Kp * N_;
    int tX = (N_ + 31) >> 5;
    int k0 = (t / tX) * 32, n0 = (t % tX) * 32;
    __shared__ float tt[32][33];
    int c = threadIdx.x & 31, r8 = threadIdx.x >> 5;
#pragma unroll
    for (int i = 0; i < 4; i++) {
        int r = r8 + i * 8;
        int k = k0 + r, n = n0 + c;
        tt[r][c] = (k < K_ && n < N_) ? src[(size_t)k * N_ + n] : 0.f;
    }
    __syncthreads();
#pragma unroll
    for (int i = 0; i < 4; i++) {
        int r = r8 + i * 8;
        int n = n0 + r, k = k0 + c;
        if (n < N_) {
            float v = tt[c][r];
            ushort_t h, l; split2(v, h, l);
            dh[(size_t)n * Kp + k] = h;
            dl[(size_t)n * Kp + k] = l;
        }
    }
}

// -------- pure-bf16 MFMA GEMM, software-pipelined; fusable epilogues:
//   lsm: log_softmax over Ndim cols;  gmax: column-max (no C write) --------
template<int MT, int NT>
__global__ __launch_bounds__(256)
void k_mgemm1(const ushort_t* __restrict__ A, int lda,
              const ushort_t* __restrict__ W, int ldw,
              float* __restrict__ Cf, int ldc,
              ushort_t* __restrict__ Ch, int ldh,
              int Ndim, int K,
              const float* __restrict__ bias1, const float* __restrict__ bias2,
              int relu, int lsm, uint_t* __restrict__ gmax) {
    constexpr int MTW = MT / 64;
    constexpr int NTT = NT / 16;
    __shared__ ushort_t As[2][MT * 40];
    __shared__ ushort_t Bs[2][NT * 40];
    __shared__ uint_t smax[NT];
    int tid = threadIdx.x;
    int w = tid >> 6, lane = tid & 63;
    int quad = lane >> 4, l16 = lane & 15;
    int m0 = blockIdx.x * MT, n0 = blockIdx.y * NT;
    uint4_t pa[MT / 64], pb[NT / 64];
    auto prefetch = [&](int k0) {
#pragma unroll
        for (int rep = 0; rep < MT / 64; rep++) {
            int idx = tid + rep * 256;
            int row = idx >> 2, q = idx & 3;
            pa[rep] = *(const uint4_t*)(A + (size_t)(m0 + row) * lda + k0 + q * 8);
        }
#pragma unroll
        for (int rep = 0; rep < NT / 64; rep++) {
            int idx = tid + rep * 256;
            int row = idx >> 2, q = idx & 3;
            uint4_t v = {0, 0, 0, 0};
            if (n0 + row < Ndim) v = *(const uint4_t*)(W + (size_t)(n0 + row) * ldw + k0 + q * 8);
            pb[rep] = v;
        }
    };
    auto stage = [&](int buf) {
#pragma unroll
        for (int rep = 0; rep < MT / 64; rep++) {
            int idx = tid + rep * 256;
            int row = idx >> 2, q = idx & 3;
            *(uint4_t*)&As[buf][row * 40 + q * 8] = pa[rep];
        }
#pragma unroll
        for (int rep = 0; rep < NT / 64; rep++) {
            int idx = tid + rep * 256;
            int row = idx >> 2, q = idx & 3;
            *(uint4_t*)&Bs[buf][row * 40 + q * 8] = pb[rep];
        }
    };
    if (gmax) {
        for (int idx = tid; idx < NT; idx += 256) smax[idx] = 0u;
    }
    floatx4 acc[MTW][NTT] = {};
    prefetch(0);
    stage(0);
    __syncthreads();
    int cur = 0;
    for (int k0 = 0; k0 < K; k0 += 32) {
        bool more = (k0 + 32 < K);
        if (more) prefetch(k0 + 32);
        short8 ah[MTW];
#pragma unroll
        for (int mt = 0; mt < MTW; mt++) {
            int r = w * (MT / 4) + mt * 16 + l16;
            ah[mt] = *(short8*)&As[cur][r * 40 + quad * 8];
        }
#pragma unroll
        for (int nt = 0; nt < NTT; nt++) {
            int r = nt * 16 + l16;
            short8 bh = *(short8*)&Bs[cur][r * 40 + quad * 8];
#pragma unroll
            for (int mt = 0; mt < MTW; mt++)
                acc[mt][nt] = __builtin_amdgcn_mfma_f32_16x16x32_bf16(ah[mt], bh, acc[mt][nt], 0, 0, 0);
        }
        if (more) stage(cur ^ 1);
        __syncthreads();
        cur ^= 1;
    }
    if (lsm) {
#pragma unroll
        for (int mt = 0; mt < MTW; mt++) {
#pragma unroll
            for (int r = 0; r < 4; r++) {
                float vv[NTT];
                float mrow = -3e38f;
#pragma unroll
                for (int nt = 0; nt < NTT; nt++) {
                    int n = n0 + nt * 16 + l16;
                    float val = (n < Ndim) ? acc[mt][nt][r] + bias1[n] : -3e38f;
                    vv[nt] = val;
                    mrow = fmaxf(mrow, val);
                }
#pragma unroll
                for (int off = 8; off >= 1; off >>= 1)
                    mrow = fmaxf(mrow, __shfl_xor(mrow, off, 64));
                float s = 0.f;
#pragma unroll
                for (int nt = 0; nt < NTT; nt++)
                    if (vv[nt] > -1e38f) s += expf(vv[nt] - mrow);
#pragma unroll
                for (int off = 8; off >= 1; off >>= 1)
                    s += __shfl_xor(s, off, 64);
                float lse = mrow + logf(s);
                int m = m0 + w * (MT / 4) + mt * 16 + quad * 4 + r;
#pragma unroll
                for (int nt = 0; nt < NTT; nt++) {
                    int n = n0 + nt * 16 + l16;
                    if (n < Ndim) Cf[(size_t)m * ldc + n] = vv[nt] - lse;
                }
            }
        }
        return;
    }
    if (gmax) {
#pragma unroll
        for (int mt = 0; mt < MTW; mt++) {
#pragma unroll
            for (int nt = 0; nt < NTT; nt++) {
#pragma unroll
                for (int r = 0; r < 4; r++) {
                    float v = acc[mt][nt][r] + bias1[nt * 16 + l16 + n0];
                    atomicMax(&smax[nt * 16 + l16], fenc(v));
                }
            }
        }
        __syncthreads();
        for (int idx = tid; idx < NT; idx += 256)
            atomicMax(&gmax[n0 + idx], smax[idx]);
        return;
    }
#pragma unroll
    for (int mt = 0; mt < MTW; mt++) {
#pragma unroll
        for (int nt = 0; nt < NTT; nt++) {
#pragma unroll
            for (int r = 0; r < 4; r++) {
                int m = m0 + w * (MT / 4) + mt * 16 + quad * 4 + r;
                int n = n0 + nt * 16 + l16;
                if (n < Ndim) {
                    float v = acc[mt][nt][r];
                    if (bias1) v += bias1[n];
                    if (bias2) v += bias2[n];
                    if (relu && v < 0.f) v = 0.f;
                    if (Cf) Cf[(size_t)m * ldc + n] = v;
                    if (Ch) Ch[(size_t)m * ldh + n] = f2bs(v);
                }
            }
        }
    }
}

// ---------------- fully-fused head MLP: l4h -> 256 -> 256 -> 128 -> 50 (lsm) --------
// One 64-row block; activations live in LDS C[64][264] (read-all-then-overwrite per
// phase; per-k-tile syncthreads orders last read before write-back).  Numerics are
// bit-identical to the previous mw1/mw2/head34 chain (same bf16 phase boundaries).
__global__ __launch_bounds__(256)
void k_head_all(const ushort_t* __restrict__ A, int lda,
                const ushort_t* __restrict__ W1, int ldw1,
                const ushort_t* __restrict__ W2, int ldw2,
                const ushort_t* __restrict__ W3, int ldw3,
                const ushort_t* __restrict__ W4, int ldw4,
                const float* __restrict__ gproj, const float* __restrict__ mb2,
                const float* __restrict__ mb3, const float* __restrict__ mb4,
                float* __restrict__ out) {
    __shared__ ushort_t As[64 * 40];
    __shared__ ushort_t Bs[256 * 40];
    __shared__ ushort_t C[64 * 264];
    int tid = threadIdx.x;
    int w = tid >> 6, lane = tid & 63;
    int quad = lane >> 4, l16 = lane & 15;
    int m0 = blockIdx.x * 64;
    // ---- P1: C = relu(A[64][326] @ W1^T + gproj), bf16 ----
    {
        floatx4 acc[16] = {};
        for (int k0 = 0; k0 < 326; k0 += 32) {
            {
                int row = tid >> 2, q = tid & 3;
                *(uint4_t*)&As[row * 40 + q * 8] =
                    *(const uint4_t*)(A + (size_t)(m0 + row) * lda + k0 + q * 8);
#pragma unroll
                for (int rep = 0; rep < 4; rep++) {
                    int idx = tid + rep * 256;
                    int br = idx >> 2, bq = idx & 3;
                    *(uint4_t*)&Bs[br * 40 + bq * 8] =
                        *(const uint4_t*)(W1 + (size_t)br * ldw1 + k0 + bq * 8);
                }
            }
            __syncthreads();
            short8 ah = *(short8*)&As[(w * 16 + l16) * 40 + quad * 8];
#pragma unroll
            for (int nt = 0; nt < 16; nt++) {
                short8 bh = *(short8*)&Bs[(nt * 16 + l16) * 40 + quad * 8];
                acc[nt] = __builtin_amdgcn_mfma_f32_16x16x32_bf16(ah, bh, acc[nt], 0, 0, 0);
            }
            __syncthreads();
        }
#pragma unroll
        for (int nt = 0; nt < 16; nt++) {
#pragma unroll
            for (int r = 0; r < 4; r++) {
                int rowl = w * 16 + quad * 4 + r;
                int col = nt * 16 + l16;
                float v = acc[nt][r] + gproj[col];
                if (v < 0.f) v = 0.f;
                C[rowl * 264 + col] = f2bs(v);
            }
        }
        __syncthreads();
    }
    // ---- P2: C = relu(C @ W2^T + mb2), bf16 (256 -> 256) ----
    {
        floatx4 acc[16] = {};
        for (int k0 = 0; k0 < 256; k0 += 32) {
            {
#pragma unroll
                for (int rep = 0; rep < 4; rep++) {
                    int idx = tid + rep * 256;
                    int br = idx >> 2, bq = idx & 3;
                    *(uint4_t*)&Bs[br * 40 + bq * 8] =
                        *(const uint4_t*)(W2 + (size_t)br * ldw2 + k0 + bq * 8);
                }
            }
            __syncthreads();
            short8 ah = *(short8*)&C[(w * 16 + l16) * 264 + k0 + quad * 8];
#pragma unroll
            for (int nt = 0; nt < 16; nt++) {
                short8 bh = *(short8*)&Bs[(nt * 16 + l16) * 40 + quad * 8];
                acc[nt] = __builtin_amdgcn_mfma_f32_16x16x32_bf16(ah, bh, acc[nt], 0, 0, 0);
            }
            __syncthreads();
        }
#pragma unroll
        for (int nt = 0; nt < 16; nt++) {
#pragma unroll
            for (int r = 0; r < 4; r++) {
                int rowl = w * 16 + quad * 4 + r;
                int col = nt * 16 + l16;
                float v = acc[nt][r] + mb2[col];
                if (v < 0.f) v = 0.f;
                C[rowl * 264 + col] = f2bs(v);
            }
        }
        __syncthreads();
    }
    // ---- P3: C[:, :128] = relu(C @ W3^T + mb3), bf16 (256 -> 128) ----
    {
        floatx4 acc[8] = {};
        for (int k0 = 0; k0 < 256; k0 += 32) {
            {
#pragma unroll
                for (int rep = 0; rep < 2; rep++) {
                    int idx = tid + rep * 256;
                    int br = idx >> 2, bq = idx & 3;
                    *(uint4_t*)&Bs[br * 40 + bq * 8] =
                        *(const uint4_t*)(W3 + (size_t)br * ldw3 + k0 + bq * 8);
                }
            }
            __syncthreads();
            short8 ah = *(short8*)&C[(w * 16 + l16) * 264 + k0 + quad * 8];
#pragma unroll
            for (int nt = 0; nt < 8; nt++) {
                short8 bh = *(short8*)&Bs[(nt * 16 + l16) * 40 + quad * 8];
                acc[nt] = __builtin_amdgcn_mfma_f32_16x16x32_bf16(ah, bh, acc[nt], 0, 0, 0);
            }
            __syncthreads();
        }
#pragma unroll
        for (int nt = 0; nt < 8; nt++) {
#pragma unroll
            for (int r = 0; r < 4; r++) {
                int rowl = w * 16 + quad * 4 + r;
                int col = nt * 16 + l16;
                float v = acc[nt][r] + mb3[col];
                if (v < 0.f) v = 0.f;
                C[rowl * 264 + col] = f2bs(v);
            }
        }
        __syncthreads();
    }
    // ---- P4: out = log_softmax(C[:, :128] @ W4^T + mb4) ----
    {
        floatx4 acc[4] = {};
        for (int k0 = 0; k0 < 128; k0 += 32) {
            {
                int row = tid >> 2, q = tid & 3;
                uint4_t v = {0, 0, 0, 0};
                if (row < 50) v = *(const uint4_t*)(W4 + (size_t)row * ldw4 + k0 + q * 8);
                *(uint4_t*)&Bs[row * 40 + q * 8] = v;
            }
            __syncthreads();
            short8 ah = *(short8*)&C[(w * 16 + l16) * 264 + k0 + quad * 8];
#pragma unroll
            for (int nt = 0; nt < 4; nt++) {
                short8 bh = *(short8*)&Bs[(nt * 16 + l16) * 40 + quad * 8];
                acc[nt] = __builtin_amdgcn_mfma_f32_16x16x32_bf16(ah, bh, acc[nt], 0, 0, 0);
            }
            __syncthreads();
        }
#pragma unroll
        for (int r = 0; r < 4; r++) {
            float vv[4];
            float mrow = -3e38f;
#pragma unroll
            for (int nt = 0; nt < 4; nt++) {
                int n = nt * 16 + l16;
                float val = (n < 50) ? acc[nt][r] + mb4[n] : -3e38f;
                vv[nt] = val;
                mrow = fmaxf(mrow, val);
            }
#pragma unroll
            for (int off = 8; off >= 1; off >>= 1)
                mrow = fmaxf(mrow, __shfl_xor(mrow, off, 64));
            float s = 0.f;
#pragma unroll
            for (int nt = 0; nt < 4; nt++)
                if (vv[nt] > -1e38f) s += expf(vv[nt] - mrow);
#pragma unroll
            for (int off = 8; off >= 1; off >>= 1)
                s += __shfl_xor(s, off, 64);
            float lse = mrow + logf(s);
            int m = m0 + w * 16 + quad * 4 + r;
#pragma unroll
            for (int nt = 0; nt < 4; nt++) {
                int n = nt * 16 + l16;
                if (n < 50) out[(size_t)m * 50 + n] = vv[nt] - lse;
            }
        }
    }
}

// ---------------- split-bf16 (3-term) MFMA GEMM ----------------
__global__ __launch_bounds__(256)
void k_mgemm3(const ushort_t* __restrict__ Ah, const ushort_t* __restrict__ Al, int lda,
              const ushort_t* __restrict__ Wh, const ushort_t* __restrict__ Wl, int ldw,
              float* __restrict__ Cf, int ldc,
              int Ndim, int K) {
    constexpr int NTT = 4;
    __shared__ ushort_t AsH[64 * 40], BsH[64 * 40], AsL[64 * 40], BsL[64 * 40];
    int tid = threadIdx.x;
    int w = tid >> 6, lane = tid & 63;
    int quad = lane >> 4, l16 = lane & 15;
    int m0 = blockIdx.y * 64, n0 = blockIdx.x * 64;
    floatx4 acc[NTT] = {};
    for (int k0 = 0; k0 < K; k0 += 32) {
        {
            int row = tid >> 2, q = tid & 3;
            size_t go = (size_t)(m0 + row) * lda + k0 + q * 8;
            *(uint4_t*)&AsH[row * 40 + q * 8] = *(const uint4_t*)(Ah + go);
            *(uint4_t*)&AsL[row * 40 + q * 8] = *(const uint4_t*)(Al + go);
            uint4_t vh = {0, 0, 0, 0}, vl = {0, 0, 0, 0};
            size_t gw = (size_t)(n0 + row) * ldw + k0 + q * 8;
            if (n0 + row < Ndim) { vh = *(const uint4_t*)(Wh + gw); vl = *(const uint4_t*)(Wl + gw); }
            *(uint4_t*)&BsH[row * 40 + q * 8] = vh;
            *(uint4_t*)&BsL[row * 40 + q * 8] = vl;
        }
        __syncthreads();
        short8 ah, al;
        {
            int r = w * 16 + l16;
            ah = *(short8*)&AsH[r * 40 + quad * 8];
            al = *(short8*)&AsL[r * 40 + quad * 8];
        }
#pragma unroll
        for (int nt = 0; nt < NTT; nt++) {
            int r = nt * 16 + l16;
            short8 bh = *(short8*)&BsH[r * 40 + quad * 8];
            short8 bl = *(short8*)&BsL[r * 40 + quad * 8];
            acc[nt] = __builtin_amdgcn_mfma_f32_16x16x32_bf16(ah, bh, acc[nt], 0, 0, 0);
            acc[nt] = __builtin_amdgcn_mfma_f32_16x16x32_bf16(ah, bl, acc[nt], 0, 0, 0);
            acc[nt] = __builtin_amdgcn_mfma_f32_16x16x32_bf16(al, bh, acc[nt], 0, 0, 0);
        }
        __syncthreads();
    }
#pragma unroll
    for (int nt = 0; nt < NTT; nt++) {
#pragma unroll
        for (int r = 0; r < 4; r++) {
            int m = m0 + w * 16 + quad * 4 + r;
            int n = n0 + nt * 16 + l16;
            if (n < Ndim) Cf[(size_t)m * ldc + n] = acc[nt][r];
        }
    }
}

// ---------------- split-bf16 MFMA pairwise distances -> packed sort keys -----------
// keys stored through cache (L3-resident for the immediately-following k_topk read).
__global__ __launch_bounds__(256)
void k_mdist(const ushort_t* __restrict__ Lh, const ushort_t* __restrict__ Ll,
             int co, int C, uint_t* __restrict__ keys) {
    __shared__ ushort_t AsH[128 * 40], AsL[128 * 40], BsH[64 * 40], BsL[64 * 40];
    __shared__ float sqa[128], sqb[64];
    int tid = threadIdx.x;
    int w = tid >> 6, lane = tid & 63;
    int quad = lane >> 4, l16 = lane & 15;
    int b = blockIdx.z, cb = b * PP;
    int i0 = blockIdx.y * 128, j0 = blockIdx.x * 64;
    floatx4 acc[2][4] = {};
    float sacc = 0.f;
    for (int k0 = 0; k0 < C; k0 += 32) {
#pragma unroll
        for (int rep = 0; rep < 8; rep++) {
            int d = tid + rep * 256;
            int row = d >> 4, c2 = d & 15;
            size_t gi = ((size_t)(cb + i0 + row) * LDH + co + k0 + c2 * 2) >> 1;
            *(uint_t*)&AsH[row * 40 + c2 * 2] = ((const uint_t*)Lh)[gi];
            *(uint_t*)&AsL[row * 40 + c2 * 2] = ((const uint_t*)Ll)[gi];
        }
#pragma unroll
        for (int rep = 0; rep < 4; rep++) {
            int d = tid + rep * 256;
            int row = d >> 4, c2 = d & 15;
            size_t gi = ((size_t)(cb + j0 + row) * LDH + co + k0 + c2 * 2) >> 1;
            *(uint_t*)&BsH[row * 40 + c2 * 2] = ((const uint_t*)Lh)[gi];
            *(uint_t*)&BsL[row * 40 + c2 * 2] = ((const uint_t*)Ll)[gi];
        }
        __syncthreads();
        if (tid < 128) {
#pragma unroll
            for (int kk = 0; kk < 16; kk++) {
                uint_t ph = *(uint_t*)&AsH[tid * 40 + kk * 2];
                uint_t pl = *(uint_t*)&AsL[tid * 40 + kk * 2];
                float v0 = bs2f((ushort_t)(ph & 0xFFFFu)) + bs2f((ushort_t)(pl & 0xFFFFu));
                sacc += v0 * v0;
                float v1 = bs2f((ushort_t)(ph >> 16)) + bs2f((ushort_t)(pl >> 16));
                sacc += v1 * v1;
            }
        } else if (tid < 192) {
            int row = tid - 128;
#pragma unroll
            for (int kk = 0; kk < 16; kk++) {
                uint_t ph = *(uint_t*)&BsH[row * 40 + kk * 2];
                uint_t pl = *(uint_t*)&BsL[row * 40 + kk * 2];
                float v0 = bs2f((ushort_t)(ph & 0xFFFFu)) + bs2f((ushort_t)(pl & 0xFFFFu));
                sacc += v0 * v0;
                float v1 = bs2f((ushort_t)(ph >> 16)) + bs2f((ushort_t)(pl >> 16));
                sacc += v1 * v1;
            }
        }
        short8 ah[2], al[2];
#pragma unroll
        for (int mt = 0; mt < 2; mt++) {
            int r = w * 32 + mt * 16 + l16;
            ah[mt] = *(short8*)&AsH[r * 40 + quad * 8];
            al[mt] = *(short8*)&AsL[r * 40 + quad * 8];
        }
#pragma unroll
        for (int nt = 0; nt < 4; nt++) {
            int r = nt * 16 + l16;
            short8 bh = *(short8*)&BsH[r * 40 + quad * 8];
            short8 bl = *(short8*)&BsL[r * 40 + quad * 8];
#pragma unroll
            for (int mt = 0; mt < 2; mt++) {
                acc[mt][nt] = __builtin_amdgcn_mfma_f32_16x16x32_bf16(ah[mt], bh, acc[mt][nt], 0, 0, 0);
                acc[mt][nt] = __builtin_amdgcn_mfma_f32_16x16x32_bf16(ah[mt], bl, acc[mt][nt], 0, 0, 0);
                acc[mt][nt] = __builtin_amdgcn_mfma_f32_16x16x32_bf16(al[mt], bh, acc[mt][nt], 0, 0, 0);
            }
        }
        __syncthreads();
    }
    if (tid < 128) sqa[tid] = sacc;
    else if (tid < 192) sqb[tid - 128] = sacc;
    __syncthreads();
#pragma unroll
    for (int mt = 0; mt < 2; mt++) {
#pragma unroll
        for (int nt = 0; nt < 4; nt++) {
#pragma unroll
            for (int r = 0; r < 4; r++) {
                int li = w * 32 + mt * 16 + quad * 4 + r;
                int lj = nt * 16 + l16;
                int il = i0 + li, jl = j0 + lj;
                float dd = sqa[li] + sqb[lj] - 2.f * acc[mt][nt][r];
                dd = (il == jl) ? 3e9f : fmaxf(dd, 0.f);
                uint_t key = (__float_as_uint(dd) & 0xFFFFF800u) | (uint_t)jl;
                keys[(size_t)(cb + il) * PP + jl] = key;
            }
        }
    }
}

// ---------------- top-30 smallest per row via packed u32 keys ----------------
__global__ __launch_bounds__(256)
void k_topk(const uint_t* __restrict__ keys, int* __restrict__ nbr) {
    int r = blockIdx.x * 4 + (threadIdx.x >> 6);
    int lane = threadIdx.x & 63;
    int base = (r / PP) * PP;
    const uint_t* row = keys + (size_t)r * PP;
    uint_t v[32];
#pragma unroll
    for (int j = 0; j < 8; j++)
        *(uint4_t*)&v[j * 4] = *(const uint4_t*)(row + lane * 4 + j * 256);
    uint_t g[8];
#pragma unroll
    for (int j = 0; j < 8; j++)
        g[j] = min(min(v[j * 4], v[j * 4 + 1]), min(v[j * 4 + 2], v[j * 4 + 3]));
    uint_t lv = g[0];
#pragma unroll
    for (int j = 1; j < 8; j++) lv = min(lv, g[j]);
    for (int sel = 0; sel < KNN; sel++) {
        uint_t bk = lv;
#pragma unroll
        for (int off = 32; off > 0; off >>= 1)
            bk = min(bk, (uint_t)__shfl_xor((int)bk, off, 64));
        uint_t bks = __builtin_amdgcn_readfirstlane(bk);
        if (lane == 0) nbr[r * KTOT + sel] = base + (int)(bks & 0x7FFu);
        int grp = (int)((bks & 0x7FFu) >> 8);
#pragma unroll
        for (int jj = 0; jj < 8; jj++)
            if (grp == jj) {
#pragma unroll
                for (int t = 0; t < 4; t++)
                    v[jj * 4 + t] = (v[jj * 4 + t] == bks) ? 0xFFFFFFFFu : v[jj * 4 + t];
                g[jj] = min(min(v[jj * 4], v[jj * 4 + 1]), min(v[jj * 4 + 2], v[jj * 4 + 3]));
            }
        lv = g[0];
#pragma unroll
        for (int j = 1; j < 8; j++) lv = min(lv, g[j]);
    }
    if (lane == 0) nbr[r * KTOT + KNN] = r;
}

// ---------------- GAT edge-softmax + aggregate, fp32 z (stages 1-2) ----------------
// z row: [3F proj | 3 src-scores | 3 dst-scores].  NN nodes/block, 192 threads.
template<int F, int NN>
__global__ __launch_bounds__(192)
void k_gat2(const float* __restrict__ z, int ldz,
            const int* __restrict__ nbr,
            const float* __restrict__ bc,
            ushort_t* __restrict__ dh, ushort_t* __restrict__ dl) {
    constexpr int TPN = 3 * F / 4;   // threads per node in aggregate (48 or 96)
    __shared__ int srcs[NN][KTOT];
    __shared__ float alpha[NN][96];
    __shared__ float part[NN][2][F];
    int tid = threadIdx.x;
    if (tid < NN * KTOT) {
        int u = tid / KTOT, k = tid % KTOT;
        int t = blockIdx.x * NN + u;
        int node = (t & 3) * PP + (t >> 2);
        srcs[u][k] = nbr[node * KTOT + k];
    }
    __syncthreads();
#pragma unroll
    for (int u2 = 0; u2 < NN; u2 += 2) {
        int u = u2 + tid / 96;       // 2 nodes per 192-thread pass; 32-lane aligned groups
        int r = tid % 96, h = r >> 5, k = r & 31;
        int t = blockIdx.x * NN + u;
        int node = (t & 3) * PP + (t >> 2);
        float e = -3e38f;
        if (k < KTOT) {
            float sv = z[(size_t)srcs[u][k] * ldz + 3 * F + h];
            float tv = z[(size_t)node * ldz + 3 * F + 3 + h];
            e = sv + tv;
            if (e < 0.f) e *= 0.2f;
        }
        float m = e;
#pragma unroll
        for (int off = 16; off >= 1; off >>= 1)
            m = fmaxf(m, __shfl_xor(m, off, 32));
        float ex = (k < KTOT) ? expf(e - m) : 0.f;
        float s = ex;
#pragma unroll
        for (int off = 16; off >= 1; off >>= 1)
            s += __shfl_xor(s, off, 32);
        alpha[u][h * 32 + k] = ex / s;
    }
    __syncthreads();
    // aggregate: thread -> (u, h, j-quad); float4 gathers, 2 vector accumulators
    {
        int u = tid / TPN, r = tid % TPN;
        int h = r / (F / 4), jq = r % (F / 4);
        const float* zb = z + h * F + jq * 4;
        floatx4 a0 = {0.f, 0.f, 0.f, 0.f}, a1 = {0.f, 0.f, 0.f, 0.f};
#pragma unroll
        for (int k = 0; k < KTOT; k += 2) {
            float a = alpha[u][h * 32 + k];
            floatx4 p = *(const floatx4*)(zb + (size_t)srcs[u][k] * ldz);
            a0 += p * a;
            if (k + 1 < KTOT) {
                float a2 = alpha[u][h * 32 + k + 1];
                floatx4 p2 = *(const floatx4*)(zb + (size_t)srcs[u][k + 1] * ldz);
                a1 += p2 * a2;
            }
        }
        floatx4 av = a0 + a1;
        if (h > 0)
            *(floatx4*)&part[u][h - 1][jq * 4] = av;
        __syncthreads();
        if (h == 0) {
            int t = blockIdx.x * NN + u;
            int node = (t & 3) * PP + (t >> 2);
            int j0 = jq * 4;
            floatx4 p0 = *(const floatx4*)&part[u][0][j0];
            floatx4 p1 = *(const floatx4*)&part[u][1][j0];
            floatx4 bcv = *(const floatx4*)&bc[j0];
            floatx4 v = av + p0 + p1 + bcv;
            ushort_t hh[4], ll[4];
#pragma unroll
            for (int q = 0; q < 4; q++) split2(v[q], hh[q], ll[q]);
            *(uint_t*)&dh[(size_t)node * LDH + j0] = (uint_t)hh[0] | ((uint_t)hh[1] << 16);
            *(uint_t*)&dh[(size_t)node * LDH + j0 + 2] = (uint_t)hh[2] | ((uint_t)hh[3] << 16);
            if (dl) {
                *(uint_t*)&dl[(size_t)node * LDH + j0] = (uint_t)ll[0] | ((uint_t)ll[1] << 16);
                *(uint_t*)&dl[(size_t)node * LDH + j0 + 2] = (uint_t)ll[2] | ((uint_t)ll[3] << 16);
            }
        }
    }
}

// ---------------- GAT edge-softmax + aggregate, bf16 z (stages 3-4) ----------------
// z stored bf16 -> half the gather bytes.  Thread owns (node, head, j-oct):
// short8 gathers (16B = 8 cols), 8 independent FMA chains.  All 192 threads active.
template<int F, int NN>
__global__ __launch_bounds__(192)
void k_gat2b(const ushort_t* __restrict__ z, int ldz,
             const int* __restrict__ nbr,
             const float* __restrict__ bc,
             ushort_t* __restrict__ dh) {
    constexpr int TPN = 3 * F / 8;   // 24 (F=64, NN=8) or 48 (F=128, NN=4)
    __shared__ int srcs[NN][KTOT];
    __shared__ float alpha[NN][96];
    __shared__ float part[NN][2][F];
    int tid = threadIdx.x;
    for (int idx = tid; idx < NN * KTOT; idx += 192) {
        int u = idx / KTOT, k = idx % KTOT;
        int t = blockIdx.x * NN + u;
        int node = (t & 3) * PP + (t >> 2);
        srcs[u][k] = nbr[node * KTOT + k];
    }
    __syncthreads();
#pragma unroll
    for (int u2 = 0; u2 < NN; u2 += 2) {
        int u = u2 + tid / 96;
        int r = tid % 96, h = r >> 5, k = r & 31;
        int t = blockIdx.x * NN + u;
        int node = (t & 3) * PP + (t >> 2);
        float e = -3e38f;
        if (k < KTOT) {
            float sv = bs2f(z[(size_t)srcs[u][k] * ldz + 3 * F + h]);
            float tv = bs2f(z[(size_t)node * ldz + 3 * F + 3 + h]);
            e = sv + tv;
            if (e < 0.f) e *= 0.2f;
        }
        float m = e;
#pragma unroll
        for (int off = 16; off >= 1; off >>= 1)
            m = fmaxf(m, __shfl_xor(m, off, 32));
        float ex = (k < KTOT) ? expf(e - m) : 0.f;
        float s = ex;
#pragma unroll
        for (int off = 16; off >= 1; off >>= 1)
            s += __shfl_xor(s, off, 32);
        alpha[u][h * 32 + k] = ex / s;
    }
    __syncthreads();
    {
        int u = tid / TPN, r = tid % TPN;
        int h = r / (F / 8), jo = r % (F / 8);
        const ushort_t* zb = z + h * F + jo * 8;
        float a[8] = {};
        for (int k = 0; k < KTOT; k++) {
            float al = alpha[u][h * 32 + k];
            short8 v = *(const short8*)(zb + (size_t)srcs[u][k] * ldz);
#pragma unroll
            for (int q = 0; q < 8; q++)
                a[q] += al * bs2f((ushort_t)v[q]);
        }
        if (h > 0) {
#pragma unroll
            for (int q = 0; q < 8; q++) part[u][h - 1][jo * 8 + q] = a[q];
        }
        __syncthreads();
        if (h == 0) {
            int t = blockIdx.x * NN + u;
            int node = (t & 3) * PP + (t >> 2);
            int j0 = jo * 8;
#pragma unroll
            for (int q2 = 0; q2 < 4; q2++) {
                float v0 = a[q2 * 2] + part[u][0][j0 + q2 * 2] + part[u][1][j0 + q2 * 2] + bc[j0 + q2 * 2];
                float v1 = a[q2 * 2 + 1] + part[u][0][j0 + q2 * 2 + 1] + part[u][1][j0 + q2 * 2 + 1] + bc[j0 + q2 * 2 + 1];
                *(uint_t*)&dh[(size_t)node * LDH + j0 + q2 * 2] =
                    (uint_t)f2bs(v0) | ((uint_t)f2bs(v1) << 16);
            }
        }
    }
}

// ---------------- gproj: decode fused column max + split-K matmul ----------------
__global__ void k_gproj(const uint_t* __restrict__ genc,
                        const float* __restrict__ mw1,
                        const float* __restrict__ mb1,
                        float* __restrict__ gproj) {
    __shared__ float gs[128];
    int kb = blockIdx.x;           // 8 blocks x 128 k
    int t = threadIdx.x;           // 256
    if (t < 128) gs[t] = fdec(genc[kb * 128 + t]);
    __syncthreads();
    float acc = (kb == 0) ? mb1[t] : 0.f;
    for (int k = 0; k < 128; k++)
        acc += gs[k] * mw1[(size_t)(326 + kb * 128 + k) * 256 + t];
    atomicAdd(&gproj[t], acc);
}

// ---------------- host side ----------------
struct WT { ushort_t *h, *l; int kp; };

extern "C" void kernel_launch(void* const* d_in, const int* in_sizes, int n_in,
                              void* d_out, int out_size, void* d_ws, size_t ws_size,
                              hipStream_t stream) {
    (void)in_sizes; (void)n_in; (void)out_size; (void)ws_size;
    const float* x    = (const float*)d_in[0];
    const float* pos  = (const float*)d_in[1];
    const float* w1   = (const float*)d_in[3];
    const float* as1  = (const float*)d_in[4];
    const float* ad1  = (const float*)d_in[5];
    const float* b1   = (const float*)d_in[6];
    const float* ml1w = (const float*)d_in[7];
    const float* ml1b = (const float*)d_in[8];
    const float* w2   = (const float*)d_in[9];
    const float* as2  = (const float*)d_in[10];
    const float* ad2  = (const float*)d_in[11];
    const float* b2   = (const float*)d_in[12];
    const float* ml2w = (const float*)d_in[13];
    const float* ml2b = (const float*)d_in[14];
    const float* w3   = (const float*)d_in[15];
    const float* as3  = (const float*)d_in[16];
    const float* ad3  = (const float*)d_in[17];
    const float* b3   = (const float*)d_in[18];
    const float* ml3w = (const float*)d_in[19];
    const float* ml3b = (const float*)d_in[20];
    const float* w4   = (const float*)d_in[21];
    const float* as4  = (const float*)d_in[22];
    const float* ad4  = (const float*)d_in[23];
    const float* b4   = (const float*)d_in[24];
    const float* ml4w = (const float*)d_in[25];
    const float* ml4b = (const float*)d_in[26];
    const float* few1 = (const float*)d_in[27];
    const float* feb1 = (const float*)d_in[28];
    const float* few2 = (const float*)d_in[29];
    const float* feb2 = (const float*)d_in[30];
    const float* mw1  = (const float*)d_in[31];
    const float* mb1  = (const float*)d_in[32];
    const float* mw2  = (const float*)d_in[33];
    const float* mb2  = (const float*)d_in[34];
    const float* mw3  = (const float*)d_in[35];
    const float* mb3  = (const float*)d_in[36];
    const float* mw4  = (const float*)d_in[37];
    const float* mb4  = (const float*)d_in[38];

    float* Wb = (float*)d_ws;
    size_t off = 0;
    auto alloc = [&](size_t n) { float* p = Wb + off; off += (n + 63) & ~(size_t)63; return p; };

    float*    dist = alloc((size_t)NPTS * PP);                  // 67 MB aliased region
    ushort_t* l4h  = (ushort_t*)alloc((size_t)NPTS * LDH / 2);
    ushort_t* l4l  = (ushort_t*)alloc((size_t)NPTS * LDH / 2);
    // genc|gproj|bcp contiguous with l4 planes -> single memset covers all
    uint_t* genc = (uint_t*)alloc(1024);                        // encoded col maxima
    float* gproj = alloc(256);
    float* bcp = alloc(320);                                    // bc1|bc2|bc3|bc4
    float* bc1 = bcp, *bc2 = bcp + 64, *bc3 = bcp + 128, *bc4 = bcp + 192;
    int*   nbr   = (int*)alloc((size_t)NPTS * KTOT);
    ushort_t* wtpool = (ushort_t*)alloc(1742336);
    float* wc1 = alloc(6 * 198);
    float* wc2 = alloc(70 * 198);
    float* wc3 = alloc(134 * 198);
    float* wc4 = alloc(198 * 390);

    // aliases inside dist region (disjoint lifetimes):
    //   dkey lives between k_mdist and k_topk; z/zb written AFTER topk consumed keys,
    //   dead before next k_mdist; hah lives in the fe phase only.
    char* d0 = (char*)dist;
    uint_t*   dkey = (uint_t*)dist;
    float*    z    = dist;
    ushort_t* zb   = (ushort_t*)dist;                           // bf16 z (stages 3-4)
    ushort_t* hah  = (ushort_t*)d0;                             // fe1 out hi (16.8MB)

    // ---- zero link4 planes + accumulators (one contiguous memset) ----
    hipMemsetAsync(l4h, 0, ((size_t)NPTS * LDH + 1600) * 4, stream); // l4h|l4l|genc|gproj|bcp

    // ---- combined GAT weights (ml-proj + scores folded into producing GEMM) ----
    {
        CAll ca;
        const float* ws_[4] = {w1, w2, w3, w4};
        const float* mlws[4] = {ml1w, ml2w, ml3w, ml4w};
        const float* ass[4] = {as1, as2, as3, as4};
        const float* ads[4] = {ad1, ad2, ad3, ad4};
        const float* bs_[4] = {b1, b2, b3, b4};
        const float* mlbs[4] = {ml1b, ml2b, ml3b, ml4b};
        float* wcs[4] = {wc1, wc2, wc3, wc4};
        float* bcs[4] = {bc1, bc2, bc3, bc4};
        int Ks[4] = {6, 70, 134, 198};
        int t = 0;
        for (int i = 0; i < 4; i++) {
            ca.w[i] = ws_[i]; ca.mlw[i] = mlws[i]; ca.as_[i] = ass[i]; ca.ad[i] = ads[i];
            ca.b[i] = bs_[i]; ca.mlb[i] = mlbs[i]; ca.wc[i] = wcs[i]; ca.bc[i] = bcs[i];
            ca.K[i] = Ks[i];
            if (i < 3) { ca.t0[i] = t; t += ((Ks[i] + 7) / 8) * 3; }
        }
        ca.t64 = t;
        int total = t + 25 * 3;   // + F=128 blocks (K=198 -> 25 slabs x 3 heads)
        k_combine_all<<<total, 128, 0, stream>>>(ca);
    }

    // ---- fused weight transpose+split (MFMA weights; combined ones from wc*) ----
    WArgs wa;
    WT wt[NSEG];
    {
        const float* srcs[NSEG] = {wc2, wc3, wc4, few1, few2, mw1, mw2, mw3, mw4};
        int Ks[NSEG] = {70, 134, 198, 326, 1024, 326, 256, 256, 128};
        int Ns[NSEG] = {198, 198, 390, 1024, 1024, 256, 256, 128, 50};
        size_t wo = 0; int tiles = 0;
        for (int i = 0; i < NSEG; i++) {
            int kp = (Ks[i] + 31) & ~31;
            wa.src[i] = srcs[i];
            wa.dst[i] = wtpool + wo;
            wa.K[i] = Ks[i]; wa.N[i] = Ns[i]; wa.Kp[i] = kp;
            wa.t0[i] = tiles;
            wt[i] = { wtpool + wo, wtpool + wo + (size_t)kp * Ns[i], kp };
            wo += (size_t)2 * kp * Ns[i];
            tiles += (kp / 32) * ((Ns[i] + 31) / 32);
        }
        k_wsplit_all<<<tiles, 256, 0, stream>>>(wa);
    }
    WT tw2 = wt[0], tw3 = wt[1], tw4 = wt[2], tfe1 = wt[3], tfe2 = wt[4],
       tmw1 = wt[5], tmw2 = wt[6], tmw3 = wt[7], tmw4 = wt[8];

    auto mg3 = [&](const ushort_t* Ah, const ushort_t* Al, int lda, WT t,
                   float* Cf, int ldc, int Nd, int K) {
        dim3 g((Nd + 63) / 64, NPTS / 64);
        k_mgemm3<<<g, 256, 0, stream>>>(Ah, Al, lda, t.h, t.l, t.kp, Cf, ldc, Nd, K);
    };
    auto mg1 = [&](int MT, int NT, const ushort_t* Ah, int lda, WT t,
                   float* Cf, int ldc, ushort_t* Ch, int ldhh,
                   int Nd, int K, const float* bb1, const float* bb2,
                   int relu, int lsm, uint_t* gmax) {
        dim3 g(NPTS / MT, (Nd + NT - 1) / NT);
        if (MT == 128 && NT == 128)
            k_mgemm1<128, 128><<<g, 256, 0, stream>>>(Ah, lda, t.h, t.kp, Cf, ldc, Ch, ldhh, Nd, K,
                bb1, bb2, relu, lsm, gmax);
        else if (MT == 128)
            k_mgemm1<128, 64><<<g, 256, 0, stream>>>(Ah, lda, t.h, t.kp, Cf, ldc, Ch, ldhh, Nd, K,
                bb1, bb2, relu, lsm, gmax);
        else
            k_mgemm1<64, 64><<<g, 256, 0, stream>>>(Ah, lda, t.h, t.kp, Cf, ldc, Ch, ldhh, Nd, K,
                bb1, bb2, relu, lsm, gmax);
    };

    dim3 dgrid(PP / 64, PP / 128, 4);
    k_build_x0<<<(NPTS * 6 + 255) / 256, 256, 0, stream>>>(x, pos, l4h, l4l);

    // ---- stage 1: knn on x0 (C=6; cols 6..31 still zero); tw1 AFTER topk; gat -> x1 ----
    k_mdist<<<dgrid, 256, 0, stream>>>(l4h, l4l, 0, 6, dkey);
    k_topk<<<NPTS / 4, 256, 0, stream>>>(dkey, nbr);
    k_tw1<<<(NPTS * 198 + 255) / 256, 256, 0, stream>>>(x, pos, wc1, z);
    k_gat2<64, 4><<<NPTS / 4, 192, 0, stream>>>(z, LDZ, nbr, bc1, l4h + 6, l4l + 6);

    // ---- stage 2: knn on x1 (C=64); split-bf16 GEMM -> z2 (proj+scores); gat -> x2 ----
    k_mdist<<<dgrid, 256, 0, stream>>>(l4h, l4l, 6, 64, dkey);
    k_topk<<<NPTS / 4, 256, 0, stream>>>(dkey, nbr);
    mg3(l4h, l4l, LDH, tw2, z, LDZ, 198, 70);
    k_gat2<64, 4><<<NPTS / 4, 192, 0, stream>>>(z, LDZ, nbr, bc2, l4h + 70, l4l + 70);

    // ---- stage 3: knn on x2 (C=64); hi-only GEMM -> zb3 (bf16); gat -> x3 (hi only) ----
    k_mdist<<<dgrid, 256, 0, stream>>>(l4h, l4l, 70, 64, dkey);
    k_topk<<<NPTS / 4, 256, 0, stream>>>(dkey, nbr);
    mg1(128, 64, l4h, LDH, tw3, nullptr, 0, zb, LDZB3, 198, 134, nullptr, nullptr, 0, 0, nullptr);
    k_gat2b<64, 8><<<NPTS / 8, 192, 0, stream>>>(zb, LDZB3, nbr, bc3, l4h + 134);

    // ---- stage 4 (reuses stage-3 nbr): GEMM -> zb4 (bf16); gat(F=128) -> x4 (hi only) ----
    mg1(128, 64, l4h, LDH, tw4, nullptr, 0, zb, LDZB4, 390, 198, nullptr, nullptr, 0, 0, nullptr);
    k_gat2b<128, 4><<<NPTS / 4, 192, 0, stream>>>(zb, LDZB4, nbr, bc4, l4h + 198);

    // ---- fe_mlp: fe1 -> bf16 acts; fe2 -> fused global column max (no C write) ----
    mg1(128, 128, l4h, LDH, tfe1, nullptr, 0, hah, 1024, 1024, 326, feb1, nullptr, 1, 0, nullptr);
    mg1(128, 128, hah, 1024, tfe2, nullptr, 0, nullptr, 0, 1024, 1024, feb2, nullptr, 0, 0, genc);
    k_gproj<<<8, 256, 0, stream>>>(genc, mw1, mb1, gproj);

    // ---- head: fully fused mw1->mw2->mw3->mw4 (+log_softmax) in one kernel ----
    k_head_all<<<NPTS / 64, 256, 0, stream>>>(l4h, LDH, tmw1.h, tmw1.kp, tmw2.h, tmw2.kp,
                                              tmw3.h, tmw3.kp, tmw4.h, tmw4.kp,
                                              gproj, mb2, mb3, mb4, (float*)d_out);
}